// Round 1
// baseline (2720.764 us; speedup 1.0000x reference)
//
#include <hip/hip_runtime.h>
#include <cstdint>

#define B_ 8
#define T_ 16
#define N_ 2048
#define CIN_ 2
#define H_ 64
#define COUT_ 64
#define KT_ 3
#define E_ 32768
#define T1_ 14
#define T2_ 12
#define G_ (B_*T1_)   // 112 graphs

__device__ __forceinline__ float sigmoidf_(float x){ return 1.f/(1.f+expf(-x)); }
__device__ __forceinline__ int rfl_(int x){ return __builtin_amdgcn_readfirstlane(x); }

// ---------------- CSR build ----------------
__global__ void k_deg_cnt(const int* __restrict__ src, const int* __restrict__ dst,
                          const float* __restrict__ ew, float* deg, int* cnt){
  int e = blockIdx.x*blockDim.x + threadIdx.x;
  if(e >= E_) return;
  int s = src[e], d = dst[e];
  float w = (s==d) ? 0.f : ew[e];
  atomicAdd(&deg[s], w);
  atomicAdd(&cnt[d], 1);
}

__global__ void k_dis(const float* __restrict__ deg, float* __restrict__ dis){
  int n = blockIdx.x*blockDim.x + threadIdx.x;
  if(n >= N_) return;
  float dg = deg[n];
  dis[n] = dg > 0.f ? rsqrtf(dg) : 0.f;
}

// exclusive scan of 2048 counts, single block of 256 threads (8 per thread)
__global__ void k_scan(const int* __restrict__ cnt, int* __restrict__ offs){
  __shared__ int sums[256];
  int tid = threadIdx.x;
  int base = tid*8;
  int loc[8]; int s = 0;
  #pragma unroll
  for(int j=0;j<8;j++){ loc[j]=s; s += cnt[base+j]; }
  sums[tid] = s; __syncthreads();
  for(int ofs=1; ofs<256; ofs<<=1){
    int t = (tid>=ofs) ? sums[tid-ofs] : 0;
    __syncthreads();
    sums[tid] += t;
    __syncthreads();
  }
  int ebase = (tid==0) ? 0 : sums[tid-1];
  #pragma unroll
  for(int j=0;j<8;j++) offs[base+j] = ebase + loc[j];
  if(tid==255) offs[N_] = sums[255];
}

__global__ void k_fill(const int* __restrict__ src, const int* __restrict__ dst,
                       const float* __restrict__ ew, const float* __restrict__ dis,
                       const int* __restrict__ offs, int* fillc,
                       int* __restrict__ csrc, float* __restrict__ cwn){
  int e = blockIdx.x*blockDim.x + threadIdx.x;
  if(e >= E_) return;
  int s = src[e], d = dst[e];
  float w = (s==d) ? 0.f : ew[e];
  float wn = -dis[s]*w*dis[d];
  int pos = offs[d] + atomicAdd(&fillc[d], 1);
  csrc[pos] = s; cwn[pos] = wn;
}

// transpose conv2 weights: w2 is (128, 64, 3) -> wt[k=ci*3+kt][co 0..127]
__global__ void k_wt(const float* __restrict__ w2, float* __restrict__ wt){
  int i = blockIdx.x*blockDim.x + threadIdx.x;
  if(i >= 192*128) return;
  int co = i % 128; int k = i / 128;
  wt[k*128 + co] = w2[co*192 + k];
}

// ---------------- temporal conv 1 + GLU ----------------
// t0[(b*14+t)*N + n][h] = (yp + xin)*sigmoid(yq)
__global__ void k_conv1(const float* __restrict__ X, const float* __restrict__ w1,
                        const float* __restrict__ b1, float* __restrict__ t0){
  int wv = rfl_(blockIdx.x*4 + (threadIdx.x>>6));
  int lane = threadIdx.x & 63;
  int n = wv % N_; int bt = wv / N_; int b = bt / T1_; int t = bt % T1_;
  const float* Xp = X + ((size_t)((b*T_ + t)*N_ + n))*CIN_;
  float xv[KT_*CIN_];
  #pragma unroll
  for(int kt=0;kt<KT_;kt++)
    #pragma unroll
    for(int ci=0;ci<CIN_;ci++)
      xv[kt*CIN_+ci] = Xp[kt*(N_*CIN_) + ci];
  float yp = b1[lane], yq = b1[lane+H_];
  #pragma unroll
  for(int ci=0;ci<CIN_;ci++)
    #pragma unroll
    for(int kt=0;kt<KT_;kt++){
      float x = xv[kt*CIN_+ci];
      yp += x * w1[ lane      *(CIN_*KT_) + ci*KT_ + kt];
      yq += x * w1[(lane+H_)*(CIN_*KT_) + ci*KT_ + kt];
    }
  float xin = (lane < CIN_) ? Xp[2*(N_*CIN_) + lane] : 0.f;
  t0[(size_t)wv*H_ + lane] = (yp + xin) * sigmoidf_(yq);
}

// ---------------- SpMM: out[row] = scale * sum_e wn*zin[g, src] (- sub[row]) ----------------
__global__ void k_spmm(const float* __restrict__ zin, const float* __restrict__ sub,
                       float* __restrict__ out, const int* __restrict__ offs,
                       const int* __restrict__ csrc, const float* __restrict__ cwn,
                       float scale){
  int wv = rfl_(blockIdx.x*4 + (threadIdx.x>>6));
  int lane = threadIdx.x & 63;
  int g = wv / N_; int d = wv % N_;
  int e0 = offs[d], e1 = offs[d+1];
  const float* zg = zin + (size_t)g*N_*H_;
  float acc = 0.f;
  for(int i=e0;i<e1;i++){
    int s = csrc[i]; float w = cwn[i];
    acc += w * zg[s*H_ + lane];
  }
  float v = scale*acc;
  if(sub) v -= sub[(size_t)wv*H_ + lane];
  out[(size_t)wv*H_ + lane] = v;
}

// ---------------- cheb GEMM stage A: acc = bias + tx0*W0 + tx1*W1 ----------------
#define NTA 8
__global__ void k_gemm01(const float* __restrict__ tx0, const float* __restrict__ tx1,
                         const float* __restrict__ W, const float* __restrict__ bias,
                         float* __restrict__ acc_out){
  int wv = rfl_(blockIdx.x*4 + (threadIdx.x>>6));
  int lane = threadIdx.x & 63;
  int row0 = wv*NTA;
  float acc[NTA];
  float bv = bias[lane];
  #pragma unroll
  for(int j=0;j<NTA;j++) acc[j] = bv;
  #pragma unroll
  for(int m=0;m<2;m++){
    const float* Z  = m ? tx1 : tx0;
    const float* Wm = W + m*(H_*H_);
    for(int h4=0; h4<H_/4; h4++){
      float4 xv[NTA];
      #pragma unroll
      for(int j=0;j<NTA;j++)
        xv[j] = *reinterpret_cast<const float4*>(Z + (size_t)(row0+j)*H_ + h4*4);
      #pragma unroll
      for(int kk=0;kk<4;kk++){
        float w = Wm[(h4*4+kk)*H_ + lane];
        #pragma unroll
        for(int j=0;j<NTA;j++){
          float x = (kk==0)?xv[j].x:(kk==1)?xv[j].y:(kk==2)?xv[j].z:xv[j].w;
          acc[j] += x * w;
        }
      }
    }
  }
  #pragma unroll
  for(int j=0;j<NTA;j++) acc_out[(size_t)(row0+j)*H_ + lane] = acc[j];
}

// ---------------- cheb GEMM stage B: acc += tx2*W2, relu, in place ----------------
__global__ void k_gemm2_relu(const float* __restrict__ tx2, const float* __restrict__ W2,
                             float* __restrict__ acc_io){
  int wv = rfl_(blockIdx.x*4 + (threadIdx.x>>6));
  int lane = threadIdx.x & 63;
  int row0 = wv*NTA;
  float acc[NTA];
  #pragma unroll
  for(int j=0;j<NTA;j++) acc[j] = acc_io[(size_t)(row0+j)*H_ + lane];
  for(int h4=0; h4<H_/4; h4++){
    float4 xv[NTA];
    #pragma unroll
    for(int j=0;j<NTA;j++)
      xv[j] = *reinterpret_cast<const float4*>(tx2 + (size_t)(row0+j)*H_ + h4*4);
    #pragma unroll
    for(int kk=0;kk<4;kk++){
      float w = W2[(h4*4+kk)*H_ + lane];
      #pragma unroll
      for(int j=0;j<NTA;j++){
        float x = (kk==0)?xv[j].x:(kk==1)?xv[j].y:(kk==2)?xv[j].z:xv[j].w;
        acc[j] += x * w;
      }
    }
  }
  #pragma unroll
  for(int j=0;j<NTA;j++) acc_io[(size_t)(row0+j)*H_ + lane] = fmaxf(acc[j], 0.f);
}

// ---------------- temporal conv 2 + GLU ----------------
#define NTC 8
__global__ void k_conv2(const float* __restrict__ tg, const float* __restrict__ wt,
                        const float* __restrict__ b2, float* __restrict__ out){
  int wv = rfl_(blockIdx.x*4 + (threadIdx.x>>6));
  int lane = threadIdx.x & 63;
  int row0 = wv*NTC;
  int n0 = row0 % N_; int bt = row0 / N_; int b = bt / T2_; int t = bt % T2_;
  const float* tgb = tg + (size_t)((b*T1_ + t)*N_)*H_;
  float accp[NTC], accq[NTC];
  float bp = b2[lane], bq = b2[lane+COUT_];
  #pragma unroll
  for(int j=0;j<NTC;j++){ accp[j]=bp; accq[j]=bq; }
  #pragma unroll
  for(int kt=0;kt<KT_;kt++){
    const float* xb = tgb + (size_t)kt*N_*H_ + (size_t)n0*H_;
    for(int c4=0;c4<H_/4;c4++){
      float4 xv[NTC];
      #pragma unroll
      for(int j=0;j<NTC;j++)
        xv[j] = *reinterpret_cast<const float4*>(xb + j*H_ + c4*4);
      #pragma unroll
      for(int kk=0;kk<4;kk++){
        int ci = c4*4+kk;
        float wp = wt[(ci*KT_+kt)*128 + lane];
        float wq = wt[(ci*KT_+kt)*128 + 64 + lane];
        #pragma unroll
        for(int j=0;j<NTC;j++){
          float x = (kk==0)?xv[j].x:(kk==1)?xv[j].y:(kk==2)?xv[j].z:xv[j].w;
          accp[j] += x * wp;
          accq[j] += x * wq;
        }
      }
    }
  }
  #pragma unroll
  for(int j=0;j<NTC;j++){
    float xin = tgb[(size_t)2*N_*H_ + (size_t)(n0+j)*H_ + lane];
    float v = (accp[j] + xin) * sigmoidf_(accq[j]);
    out[((size_t)(b*T2_ + t)*N_ + n0 + j)*H_ + lane] = v;
  }
}

extern "C" void kernel_launch(void* const* d_in, const int* in_sizes, int n_in,
                              void* d_out, int out_size, void* d_ws, size_t ws_size,
                              hipStream_t stream){
  (void)in_sizes; (void)n_in; (void)out_size; (void)ws_size;
  const float* X  = (const float*)d_in[0];
  const int*   ei = (const int*)d_in[1];
  const float* ew = (const float*)d_in[2];
  const float* w1 = (const float*)d_in[3];
  const float* b1 = (const float*)d_in[4];
  const float* cw = (const float*)d_in[5];
  const float* cb = (const float*)d_in[6];
  const float* w2 = (const float*)d_in[7];
  const float* b2 = (const float*)d_in[8];
  float* out = (float*)d_out;

  char* ws = (char*)d_ws;
  const size_t BUF = (size_t)G_*N_*H_*sizeof(float); // 58,720,256 B
  float* buf0 = (float*)(ws);            // t0, later tx2 (in place)
  float* buf1 = (float*)(ws + BUF);      // tx1
  float* buf2 = (float*)(ws + 2*BUF);    // acc -> tg
  char* sm = ws + 3*BUF;
  float* deg   = (float*)(sm);               // 8192 B
  float* dis   = (float*)(sm + 8192);        // 8192 B
  int*   cnt   = (int*)  (sm + 16384);       // 8192 B
  int*   fillc = (int*)  (sm + 24576);       // 8192 B
  int*   offs  = (int*)  (sm + 32768);       // 8196 B (padded 8448)
  int*   csrc  = (int*)  (sm + 41216);       // 131072 B
  float* cwn   = (float*)(sm + 41216 + 131072); // 131072 B
  float* wt    = (float*)(sm + 41216 + 262144); // 98304 B

  const int* src = ei;
  const int* dst = ei + E_;

  hipMemsetAsync(deg,   0, 8192, stream);
  hipMemsetAsync(cnt,   0, 8192, stream);
  hipMemsetAsync(fillc, 0, 8192, stream);

  k_deg_cnt<<<E_/256, 256, 0, stream>>>(src, dst, ew, deg, cnt);
  k_dis    <<<N_/256, 256, 0, stream>>>(deg, dis);
  k_scan   <<<1,      256, 0, stream>>>(cnt, offs);
  k_fill   <<<E_/256, 256, 0, stream>>>(src, dst, ew, dis, offs, fillc, csrc, cwn);
  k_wt     <<<(192*128)/256, 256, 0, stream>>>(w2, wt);

  // stage 1: temporal conv1 + GLU -> buf0 (t0)
  k_conv1<<<(G_*N_)/4, 256, 0, stream>>>(X, w1, b1, buf0);

  // tx1 = L t0 -> buf1
  k_spmm<<<(G_*N_)/4, 256, 0, stream>>>(buf0, nullptr, buf1, offs, csrc, cwn, 1.f);

  // acc = bias + t0*W0 + tx1*W1 -> buf2
  k_gemm01<<<(G_*N_)/(4*NTA), 256, 0, stream>>>(buf0, buf1, cw, cb, buf2);

  // tx2 = 2 L tx1 - t0 -> buf0 (in place over t0)
  k_spmm<<<(G_*N_)/4, 256, 0, stream>>>(buf1, buf0, buf0, offs, csrc, cwn, 2.f);

  // tg = relu(acc + tx2*W2) -> buf2
  k_gemm2_relu<<<(G_*N_)/(4*NTA), 256, 0, stream>>>(buf0, cw + 2*H_*H_, buf2);

  // stage 3: temporal conv2 + GLU -> out
  k_conv2<<<(B_*T2_*N_)/(4*NTC), 256, 0, stream>>>(buf2, wt, b2, out);
}

// Round 2
// 965.891 us; speedup vs baseline: 2.8168x; 2.8168x over previous
//
#include <hip/hip_runtime.h>
#include <cstdint>

#define B_ 8
#define T_ 16
#define N_ 2048
#define CIN_ 2
#define H_ 64
#define COUT_ 64
#define KT_ 3
#define E_ 32768
#define T1_ 14
#define T2_ 12
#define G_ (B_*T1_)   // 112 graphs

__device__ __forceinline__ float sigmoidf_(float x){ return 1.f/(1.f+expf(-x)); }
__device__ __forceinline__ int rfl_(int x){ return __builtin_amdgcn_readfirstlane(x); }

// ---------------- CSR build ----------------
__global__ void k_deg_cnt(const int* __restrict__ src, const int* __restrict__ dst,
                          const float* __restrict__ ew, float* deg, int* cnt){
  int e = blockIdx.x*blockDim.x + threadIdx.x;
  if(e >= E_) return;
  int s = src[e], d = dst[e];
  float w = (s==d) ? 0.f : ew[e];
  atomicAdd(&deg[s], w);
  atomicAdd(&cnt[d], 1);
}

__global__ void k_dis(const float* __restrict__ deg, float* __restrict__ dis){
  int n = blockIdx.x*blockDim.x + threadIdx.x;
  if(n >= N_) return;
  float dg = deg[n];
  dis[n] = dg > 0.f ? rsqrtf(dg) : 0.f;
}

// exclusive scan of 2048 counts, single block of 256 threads (8 per thread)
__global__ void k_scan(const int* __restrict__ cnt, int* __restrict__ offs){
  __shared__ int sums[256];
  int tid = threadIdx.x;
  int base = tid*8;
  int loc[8]; int s = 0;
  #pragma unroll
  for(int j=0;j<8;j++){ loc[j]=s; s += cnt[base+j]; }
  sums[tid] = s; __syncthreads();
  for(int ofs=1; ofs<256; ofs<<=1){
    int t = (tid>=ofs) ? sums[tid-ofs] : 0;
    __syncthreads();
    sums[tid] += t;
    __syncthreads();
  }
  int ebase = (tid==0) ? 0 : sums[tid-1];
  #pragma unroll
  for(int j=0;j<8;j++) offs[base+j] = ebase + loc[j];
  if(tid==255) offs[N_] = sums[255];
}

__global__ void k_fill(const int* __restrict__ src, const int* __restrict__ dst,
                       const float* __restrict__ ew, const float* __restrict__ dis,
                       const int* __restrict__ offs, int* fillc,
                       int* __restrict__ csrc, float* __restrict__ cwn){
  int e = blockIdx.x*blockDim.x + threadIdx.x;
  if(e >= E_) return;
  int s = src[e], d = dst[e];
  float w = (s==d) ? 0.f : ew[e];
  float wn = -dis[s]*w*dis[d];
  int pos = offs[d] + atomicAdd(&fillc[d], 1);
  csrc[pos] = s; cwn[pos] = wn;
}

// transpose conv2 weights: w2 is (128, 64, 3) -> wt[(kt*64+ci)*128 + co]
__global__ void k_wt(const float* __restrict__ w2, float* __restrict__ wt){
  int i = blockIdx.x*blockDim.x + threadIdx.x;
  if(i >= 192*128) return;
  int co = i % 128; int k = i / 128;   // k = kt*64 + ci
  int kt = k / 64; int ci = k % 64;
  wt[(kt*H_ + ci)*128 + co] = w2[co*192 + ci*KT_ + kt];
}

// ---------------- temporal conv 1 + GLU ----------------
__global__ void k_conv1(const float* __restrict__ X, const float* __restrict__ w1,
                        const float* __restrict__ b1, float* __restrict__ t0){
  int wv = rfl_(blockIdx.x*4 + (threadIdx.x>>6));
  int lane = threadIdx.x & 63;
  int n = wv % N_; int bt = wv / N_; int b = bt / T1_; int t = bt % T1_;
  const float* Xp = X + ((size_t)((b*T_ + t)*N_ + n))*CIN_;
  float xv[KT_*CIN_];
  #pragma unroll
  for(int kt=0;kt<KT_;kt++)
    #pragma unroll
    for(int ci=0;ci<CIN_;ci++)
      xv[kt*CIN_+ci] = Xp[kt*(N_*CIN_) + ci];
  float yp = b1[lane], yq = b1[lane+H_];
  #pragma unroll
  for(int ci=0;ci<CIN_;ci++)
    #pragma unroll
    for(int kt=0;kt<KT_;kt++){
      float x = xv[kt*CIN_+ci];
      yp += x * w1[ lane      *(CIN_*KT_) + ci*KT_ + kt];
      yq += x * w1[(lane+H_)*(CIN_*KT_) + ci*KT_ + kt];
    }
  float xin = (lane < CIN_) ? Xp[2*(N_*CIN_) + lane] : 0.f;
  t0[(size_t)wv*H_ + lane] = (yp + xin) * sigmoidf_(yq);
}

// ---------------- SpMM ----------------
__global__ void k_spmm(const float* __restrict__ zin, const float* __restrict__ sub,
                       float* __restrict__ out, const int* __restrict__ offs,
                       const int* __restrict__ csrc, const float* __restrict__ cwn,
                       float scale){
  int wv = rfl_(blockIdx.x*4 + (threadIdx.x>>6));
  int lane = threadIdx.x & 63;
  int g = wv / N_; int d = wv % N_;
  int e0 = offs[d], e1 = offs[d+1];
  const float* zg = zin + (size_t)g*N_*H_;
  float acc = 0.f;
  for(int i=e0;i<e1;i++){
    int s = csrc[i]; float w = cwn[i];
    acc += w * zg[s*H_ + lane];
  }
  float v = scale*acc;
  if(sub) v -= sub[(size_t)wv*H_ + lane];
  out[(size_t)wv*H_ + lane] = v;
}

// ---------------- cheb GEMM stage A: acc = bias + tx0*W0 + tx1*W1 ----------------
// one live float4; weights hoisted per K-chunk; 16 rows per wave
#define NTA 16
__global__ void k_gemm01(const float* __restrict__ tx0, const float* __restrict__ tx1,
                         const float* __restrict__ W, const float* __restrict__ bias,
                         float* __restrict__ acc_out){
  int wv = rfl_(blockIdx.x*4 + (threadIdx.x>>6));
  int lane = threadIdx.x & 63;
  int row0 = wv*NTA;
  float acc[NTA];
  float bv = bias[lane];
  #pragma unroll
  for(int j=0;j<NTA;j++) acc[j] = bv;
  #pragma unroll
  for(int m=0;m<2;m++){
    const float* Z  = m ? tx1 : tx0;
    const float* Wm = W + m*(H_*H_);
    const float* Zr = Z + (size_t)row0*H_;
    #pragma unroll 4
    for(int h4=0; h4<H_/4; h4++){
      float w4[4];
      #pragma unroll
      for(int kk=0;kk<4;kk++) w4[kk] = Wm[(h4*4+kk)*H_ + lane];
      #pragma unroll
      for(int j=0;j<NTA;j++){
        float4 xv = *reinterpret_cast<const float4*>(Zr + j*H_ + h4*4);
        acc[j] += xv.x*w4[0] + xv.y*w4[1] + xv.z*w4[2] + xv.w*w4[3];
      }
    }
  }
  #pragma unroll
  for(int j=0;j<NTA;j++) acc_out[(size_t)(row0+j)*H_ + lane] = acc[j];
}

// ---------------- cheb GEMM stage B: acc += tx2*W2, relu, in place ----------------
__global__ void k_gemm2_relu(const float* __restrict__ tx2, const float* __restrict__ W2,
                             float* __restrict__ acc_io){
  int wv = rfl_(blockIdx.x*4 + (threadIdx.x>>6));
  int lane = threadIdx.x & 63;
  int row0 = wv*NTA;
  float acc[NTA];
  #pragma unroll
  for(int j=0;j<NTA;j++) acc[j] = acc_io[(size_t)(row0+j)*H_ + lane];
  const float* Zr = tx2 + (size_t)row0*H_;
  #pragma unroll 4
  for(int h4=0; h4<H_/4; h4++){
    float w4[4];
    #pragma unroll
    for(int kk=0;kk<4;kk++) w4[kk] = W2[(h4*4+kk)*H_ + lane];
    #pragma unroll
    for(int j=0;j<NTA;j++){
      float4 xv = *reinterpret_cast<const float4*>(Zr + j*H_ + h4*4);
      acc[j] += xv.x*w4[0] + xv.y*w4[1] + xv.z*w4[2] + xv.w*w4[3];
    }
  }
  #pragma unroll
  for(int j=0;j<NTA;j++) acc_io[(size_t)(row0+j)*H_ + lane] = fmaxf(acc[j], 0.f);
}

// ---------------- temporal conv 2 + GLU ----------------
// 16 rows per wave, one live float4, weights (8 scalars) hoisted per K-chunk
#define NTC 16
__global__ void k_conv2(const float* __restrict__ tg, const float* __restrict__ wt,
                        const float* __restrict__ b2, float* __restrict__ out){
  int wv = rfl_(blockIdx.x*4 + (threadIdx.x>>6));
  int lane = threadIdx.x & 63;
  int row0 = wv*NTC;
  int n0 = row0 % N_; int bt = row0 / N_; int b = bt / T2_; int t = bt % T2_;
  const float* tgb = tg + (size_t)((b*T1_ + t)*N_)*H_;
  float accp[NTC], accq[NTC];
  float bp = b2[lane], bq = b2[lane+COUT_];
  #pragma unroll
  for(int j=0;j<NTC;j++){ accp[j]=bp; accq[j]=bq; }
  #pragma unroll
  for(int kt=0;kt<KT_;kt++){
    const float* xb = tgb + (size_t)kt*N_*H_ + (size_t)n0*H_;
    const float* wb = wt + kt*H_*128;
    #pragma unroll 2
    for(int c4=0;c4<H_/4;c4++){
      float wp[4], wq[4];
      #pragma unroll
      for(int kk=0;kk<4;kk++){
        wp[kk] = wb[(c4*4+kk)*128 + lane];
        wq[kk] = wb[(c4*4+kk)*128 + 64 + lane];
      }
      #pragma unroll
      for(int j=0;j<NTC;j++){
        float4 xv = *reinterpret_cast<const float4*>(xb + j*H_ + c4*4);
        accp[j] += xv.x*wp[0] + xv.y*wp[1] + xv.z*wp[2] + xv.w*wp[3];
        accq[j] += xv.x*wq[0] + xv.y*wq[1] + xv.z*wq[2] + xv.w*wq[3];
      }
    }
  }
  #pragma unroll
  for(int j=0;j<NTC;j++){
    float xin = tgb[(size_t)2*N_*H_ + (size_t)(n0+j)*H_ + lane];
    float v = (accp[j] + xin) * sigmoidf_(accq[j]);
    out[((size_t)(b*T2_ + t)*N_ + n0 + j)*H_ + lane] = v;
  }
}

extern "C" void kernel_launch(void* const* d_in, const int* in_sizes, int n_in,
                              void* d_out, int out_size, void* d_ws, size_t ws_size,
                              hipStream_t stream){
  (void)in_sizes; (void)n_in; (void)out_size; (void)ws_size;
  const float* X  = (const float*)d_in[0];
  const int*   ei = (const int*)d_in[1];
  const float* ew = (const float*)d_in[2];
  const float* w1 = (const float*)d_in[3];
  const float* b1 = (const float*)d_in[4];
  const float* cw = (const float*)d_in[5];
  const float* cb = (const float*)d_in[6];
  const float* w2 = (const float*)d_in[7];
  const float* b2 = (const float*)d_in[8];
  float* out = (float*)d_out;

  char* ws = (char*)d_ws;
  const size_t BUF = (size_t)G_*N_*H_*sizeof(float); // 58,720,256 B
  float* buf0 = (float*)(ws);            // t0, later tx2 (in place)
  float* buf1 = (float*)(ws + BUF);      // tx1
  float* buf2 = (float*)(ws + 2*BUF);    // acc -> tg
  char* sm = ws + 3*BUF;
  float* deg   = (float*)(sm);               // 8192 B
  float* dis   = (float*)(sm + 8192);        // 8192 B
  int*   cnt   = (int*)  (sm + 16384);       // 8192 B
  int*   fillc = (int*)  (sm + 24576);       // 8192 B
  int*   offs  = (int*)  (sm + 32768);       // 8196 B (padded 8448)
  int*   csrc  = (int*)  (sm + 41216);       // 131072 B
  float* cwn   = (float*)(sm + 41216 + 131072); // 131072 B
  float* wt    = (float*)(sm + 41216 + 262144); // 98304 B

  const int* src = ei;
  const int* dst = ei + E_;

  hipMemsetAsync(deg,   0, 8192, stream);
  hipMemsetAsync(cnt,   0, 8192, stream);
  hipMemsetAsync(fillc, 0, 8192, stream);

  k_deg_cnt<<<E_/256, 256, 0, stream>>>(src, dst, ew, deg, cnt);
  k_dis    <<<N_/256, 256, 0, stream>>>(deg, dis);
  k_scan   <<<1,      256, 0, stream>>>(cnt, offs);
  k_fill   <<<E_/256, 256, 0, stream>>>(src, dst, ew, dis, offs, fillc, csrc, cwn);
  k_wt     <<<(192*128)/256, 256, 0, stream>>>(w2, wt);

  // stage 1: temporal conv1 + GLU -> buf0 (t0)
  k_conv1<<<(G_*N_)/4, 256, 0, stream>>>(X, w1, b1, buf0);

  // tx1 = L t0 -> buf1
  k_spmm<<<(G_*N_)/4, 256, 0, stream>>>(buf0, nullptr, buf1, offs, csrc, cwn, 1.f);

  // acc = bias + t0*W0 + tx1*W1 -> buf2
  k_gemm01<<<(G_*N_)/(4*NTA), 256, 0, stream>>>(buf0, buf1, cw, cb, buf2);

  // tx2 = 2 L tx1 - t0 -> buf0 (in place over t0)
  k_spmm<<<(G_*N_)/4, 256, 0, stream>>>(buf1, buf0, buf0, offs, csrc, cwn, 2.f);

  // tg = relu(acc + tx2*W2) -> buf2
  k_gemm2_relu<<<(G_*N_)/(4*NTA), 256, 0, stream>>>(buf0, cw + 2*H_*H_, buf2);

  // stage 3: temporal conv2 + GLU -> out
  k_conv2<<<(B_*T2_*N_)/(4*NTC), 256, 0, stream>>>(buf2, wt, b2, out);
}

// Round 3
// 489.083 us; speedup vs baseline: 5.5630x; 1.9749x over previous
//
#include <hip/hip_runtime.h>
#include <cstdint>

#define B_ 8
#define T_ 16
#define N_ 2048
#define CIN_ 2
#define H_ 64
#define COUT_ 64
#define KT_ 3
#define E_ 32768
#define T1_ 14
#define T2_ 12
#define G_ (B_*T1_)   // 112 graphs

typedef __attribute__((ext_vector_type(8))) short bf16x8;
typedef __attribute__((ext_vector_type(4))) float f32x4;
typedef unsigned short ushort_;

__device__ __forceinline__ float sigmoidf_(float x){ return 1.f/(1.f+expf(-x)); }
__device__ __forceinline__ int rfl_(int x){ return __builtin_amdgcn_readfirstlane(x); }

__device__ __forceinline__ ushort_ f2b(float x){
  union {float f; uint32_t u;} v; v.f = x;
  uint32_t r = (v.u + 0x7FFFu + ((v.u>>16)&1u)) >> 16;
  return (ushort_)r;
}
__device__ __forceinline__ float b2f(ushort_ x){
  union {uint32_t u; float f;} v; v.u = ((uint32_t)x)<<16;
  return v.f;
}

// ---------------- CSR build ----------------
__global__ void k_deg_cnt(const int* __restrict__ src, const int* __restrict__ dst,
                          const float* __restrict__ ew, float* deg, int* cnt){
  int e = blockIdx.x*blockDim.x + threadIdx.x;
  if(e >= E_) return;
  int s = src[e], d = dst[e];
  float w = (s==d) ? 0.f : ew[e];
  atomicAdd(&deg[s], w);
  atomicAdd(&cnt[d], 1);
}

__global__ void k_dis(const float* __restrict__ deg, float* __restrict__ dis){
  int n = blockIdx.x*blockDim.x + threadIdx.x;
  if(n >= N_) return;
  float dg = deg[n];
  dis[n] = dg > 0.f ? rsqrtf(dg) : 0.f;
}

__global__ void k_scan(const int* __restrict__ cnt, int* __restrict__ offs){
  __shared__ int sums[256];
  int tid = threadIdx.x;
  int base = tid*8;
  int loc[8]; int s = 0;
  #pragma unroll
  for(int j=0;j<8;j++){ loc[j]=s; s += cnt[base+j]; }
  sums[tid] = s; __syncthreads();
  for(int ofs=1; ofs<256; ofs<<=1){
    int t = (tid>=ofs) ? sums[tid-ofs] : 0;
    __syncthreads();
    sums[tid] += t;
    __syncthreads();
  }
  int ebase = (tid==0) ? 0 : sums[tid-1];
  #pragma unroll
  for(int j=0;j<8;j++) offs[base+j] = ebase + loc[j];
  if(tid==255) offs[N_] = sums[255];
}

__global__ void k_fill(const int* __restrict__ src, const int* __restrict__ dst,
                       const float* __restrict__ ew, const float* __restrict__ dis,
                       const int* __restrict__ offs, int* fillc,
                       int* __restrict__ csrc, float* __restrict__ cwn){
  int e = blockIdx.x*blockDim.x + threadIdx.x;
  if(e >= E_) return;
  int s = src[e], d = dst[e];
  float w = (s==d) ? 0.f : ew[e];
  float wn = -dis[s]*w*dis[d];
  int pos = offs[d] + atomicAdd(&fillc[d], 1);
  csrc[pos] = s; cwn[pos] = wn;
}

// ---- weight prepack into MFMA B-fragment layout (bf16) ----
// cheb: B[k=kk*64+h][col] = cw[(kk*64+h)*64+col], 192x64
// Bp[((c*4+n)*64+lane)*8+j] = B[c*32+(lane>>4)*8+j][n*16+(lane&15)]
__global__ void k_prep_cheb(const float* __restrict__ cw, ushort_* __restrict__ Bp){
  int i = blockIdx.x*blockDim.x + threadIdx.x;
  if(i >= 6*4*64) return;
  int lane = i & 63; int cn = i >> 6; int c = cn >> 2; int n = cn & 3;
  #pragma unroll
  for(int j=0;j<8;j++){
    int k = c*32 + (lane>>4)*8 + j;
    int col = n*16 + (lane&15);
    Bp[(size_t)i*8 + j] = f2b(cw[(size_t)k*64 + col]);
  }
}
// conv2: B2[k=kt*64+ci][co] = w2[co*192 + ci*3 + kt], 192x128
__global__ void k_prep_conv2(const float* __restrict__ w2, ushort_* __restrict__ Bp2){
  int i = blockIdx.x*blockDim.x + threadIdx.x;
  if(i >= 6*8*64) return;
  int lane = i & 63; int cn = i >> 6; int c = cn >> 3; int n = cn & 7;
  #pragma unroll
  for(int j=0;j<8;j++){
    int k = c*32 + (lane>>4)*8 + j;
    int co = n*16 + (lane&15);
    int kt = k >> 6, ci = k & 63;
    Bp2[(size_t)i*8 + j] = f2b(w2[(size_t)co*192 + ci*3 + kt]);
  }
}

// ---------------- temporal conv 1 + GLU -> bf16 ----------------
__global__ void k_conv1(const float* __restrict__ X, const float* __restrict__ w1,
                        const float* __restrict__ b1, ushort_* __restrict__ t0){
  int wv = rfl_(blockIdx.x*4 + (threadIdx.x>>6));
  int lane = threadIdx.x & 63;
  int n = wv % N_; int bt = wv / N_; int b = bt / T1_; int t = bt % T1_;
  const float* Xp = X + ((size_t)((b*T_ + t)*N_ + n))*CIN_;
  float xv[KT_*CIN_];
  #pragma unroll
  for(int kt=0;kt<KT_;kt++)
    #pragma unroll
    for(int ci=0;ci<CIN_;ci++)
      xv[kt*CIN_+ci] = Xp[kt*(N_*CIN_) + ci];
  float yp = b1[lane], yq = b1[lane+H_];
  #pragma unroll
  for(int ci=0;ci<CIN_;ci++)
    #pragma unroll
    for(int kt=0;kt<KT_;kt++){
      float x = xv[kt*CIN_+ci];
      yp += x * w1[ lane      *(CIN_*KT_) + ci*KT_ + kt];
      yq += x * w1[(lane+H_)*(CIN_*KT_) + ci*KT_ + kt];
    }
  float xin = (lane < CIN_) ? Xp[2*(N_*CIN_) + lane] : 0.f;
  t0[(size_t)wv*H_ + lane] = f2b((yp + xin) * sigmoidf_(yq));
}

// ---------------- SpMM (bf16 in/out, fp32 accum) ----------------
__global__ void k_spmm(const ushort_* __restrict__ zin, const ushort_* __restrict__ sub,
                       ushort_* __restrict__ out, const int* __restrict__ offs,
                       const int* __restrict__ csrc, const float* __restrict__ cwn,
                       float scale){
  int wv = rfl_(blockIdx.x*4 + (threadIdx.x>>6));
  int lane = threadIdx.x & 63;
  int g = wv / N_; int d = wv % N_;
  int e0 = offs[d], e1 = offs[d+1];
  const ushort_* zg = zin + (size_t)g*N_*H_;
  float acc = 0.f;
  for(int i=e0;i<e1;i++){
    int s = csrc[i]; float w = cwn[i];
    acc += w * b2f(zg[s*H_ + lane]);
  }
  float v = scale*acc;
  if(sub) v -= b2f(sub[(size_t)wv*H_ + lane]);
  out[(size_t)wv*H_ + lane] = f2b(v);
}

// ---------------- cheb fused GEMM via MFMA: tg = relu(bias + [tx0|tx1|tx2] @ Wcat) ----------------
// M=G*N, K=192 (6 chunks of 32), N=64. 4 waves/block, 32 rows/wave.
__global__ void k_cheb_mfma(const ushort_* __restrict__ tx0, const ushort_* __restrict__ tx1,
                            const ushort_* __restrict__ tx2, const ushort_* __restrict__ Bp,
                            const float* __restrict__ bias, ushort_* __restrict__ tg){
  int lane = threadIdx.x & 63;
  int wv = threadIdx.x >> 6;
  int row0 = (blockIdx.x*4 + wv)*32;
  f32x4 acc[2][4] = {};
  #pragma unroll
  for(int c=0;c<6;c++){
    const ushort_* s = (c>>1)==0 ? tx0 : ((c>>1)==1 ? tx1 : tx2);
    int eoff = (c&1)*32 + (lane>>4)*8;
    bf16x8 a0 = *(const bf16x8*)(s + (size_t)(row0 +      (lane&15))*H_ + eoff);
    bf16x8 a1 = *(const bf16x8*)(s + (size_t)(row0 + 16 + (lane&15))*H_ + eoff);
    #pragma unroll
    for(int n=0;n<4;n++){
      bf16x8 bfr = *(const bf16x8*)(Bp + ((size_t)(c*4+n)*64 + lane)*8);
      acc[0][n] = __builtin_amdgcn_mfma_f32_16x16x32_bf16(a0, bfr, acc[0][n], 0,0,0);
      acc[1][n] = __builtin_amdgcn_mfma_f32_16x16x32_bf16(a1, bfr, acc[1][n], 0,0,0);
    }
  }
  #pragma unroll
  for(int rg=0; rg<2; rg++)
    #pragma unroll
    for(int n=0;n<4;n++){
      int col = n*16 + (lane&15);
      float bv = bias[col];
      #pragma unroll
      for(int r=0;r<4;r++){
        int row = row0 + rg*16 + (lane>>4)*4 + r;
        float v = fmaxf(acc[rg][n][r] + bv, 0.f);
        tg[(size_t)row*H_ + col] = f2b(v);
      }
    }
}

// ---------------- conv2 via MFMA: out = (P + bp + xin) * sigmoid(Q + bq) ----------------
// per (b,t): M=2048 rows, K=192 (3 temporal slabs x 64ch), N=128 (p|q)
__global__ void k_conv2_mfma(const ushort_* __restrict__ tg, const ushort_* __restrict__ Bp2,
                             const float* __restrict__ b2, float* __restrict__ out){
  int lane = threadIdx.x & 63;
  int wv = threadIdx.x >> 6;
  int blk = blockIdx.x;          // 96*16
  int bt = blk >> 4; int nblk = blk & 15;
  int b = bt / T2_, t = bt % T2_;
  int n0 = nblk*128 + wv*32;
  const ushort_* base = tg + (size_t)(b*T1_ + t)*N_*H_;
  f32x4 acc[2][8] = {};
  #pragma unroll
  for(int c=0;c<6;c++){
    const ushort_* s = base + (size_t)(c>>1)*N_*H_;
    int eoff = (c&1)*32 + (lane>>4)*8;
    bf16x8 a0 = *(const bf16x8*)(s + (size_t)(n0 +      (lane&15))*H_ + eoff);
    bf16x8 a1 = *(const bf16x8*)(s + (size_t)(n0 + 16 + (lane&15))*H_ + eoff);
    #pragma unroll
    for(int n=0;n<8;n++){
      bf16x8 bfr = *(const bf16x8*)(Bp2 + ((size_t)(c*8+n)*64 + lane)*8);
      acc[0][n] = __builtin_amdgcn_mfma_f32_16x16x32_bf16(a0, bfr, acc[0][n], 0,0,0);
      acc[1][n] = __builtin_amdgcn_mfma_f32_16x16x32_bf16(a1, bfr, acc[1][n], 0,0,0);
    }
  }
  const ushort_* xslab = base + (size_t)2*N_*H_;
  float* ob = out + (size_t)(b*T2_ + t)*N_*H_;
  #pragma unroll
  for(int rg=0;rg<2;rg++)
    #pragma unroll
    for(int n=0;n<4;n++){
      int col = n*16 + (lane&15);
      float bp = b2[col], bq = b2[col+COUT_];
      #pragma unroll
      for(int r=0;r<4;r++){
        int row = n0 + rg*16 + (lane>>4)*4 + r;
        float xin = b2f(xslab[(size_t)row*H_ + col]);
        float p = acc[rg][n][r] + bp + xin;
        float q = acc[rg][n+4][r] + bq;
        ob[(size_t)row*H_ + col] = p * sigmoidf_(q);
      }
    }
}

extern "C" void kernel_launch(void* const* d_in, const int* in_sizes, int n_in,
                              void* d_out, int out_size, void* d_ws, size_t ws_size,
                              hipStream_t stream){
  (void)in_sizes; (void)n_in; (void)out_size; (void)ws_size;
  const float* X  = (const float*)d_in[0];
  const int*   ei = (const int*)d_in[1];
  const float* ew = (const float*)d_in[2];
  const float* w1 = (const float*)d_in[3];
  const float* b1 = (const float*)d_in[4];
  const float* cw = (const float*)d_in[5];
  const float* cb = (const float*)d_in[6];
  const float* w2 = (const float*)d_in[7];
  const float* b2 = (const float*)d_in[8];
  float* out = (float*)d_out;

  char* ws = (char*)d_ws;
  const size_t BUF = (size_t)G_*N_*H_*sizeof(ushort_); // 29,360,128 B
  ushort_* t0  = (ushort_*)(ws);
  ushort_* tx1 = (ushort_*)(ws + BUF);
  ushort_* tx2 = (ushort_*)(ws + 2*BUF);
  ushort_* tg  = (ushort_*)(ws + 3*BUF);
  char* sm = ws + 4*BUF;
  float* deg   = (float*)(sm);               // 8192
  float* dis   = (float*)(sm + 8192);        // 8192
  int*   cnt   = (int*)  (sm + 16384);       // 8192
  int*   fillc = (int*)  (sm + 24576);       // 8192
  int*   offs  = (int*)  (sm + 32768);       // 8448
  int*   csrc  = (int*)  (sm + 41216);       // 131072
  float* cwn   = (float*)(sm + 41216 + 131072); // 131072
  ushort_* Bp  = (ushort_*)(sm + 41216 + 262144);          // 24576
  ushort_* Bp2 = (ushort_*)(sm + 41216 + 262144 + 24576);  // 49152

  const int* src = ei;
  const int* dst = ei + E_;

  hipMemsetAsync(deg,   0, 8192, stream);
  hipMemsetAsync(cnt,   0, 8192, stream);
  hipMemsetAsync(fillc, 0, 8192, stream);

  k_deg_cnt<<<E_/256, 256, 0, stream>>>(src, dst, ew, deg, cnt);
  k_dis    <<<N_/256, 256, 0, stream>>>(deg, dis);
  k_scan   <<<1,      256, 0, stream>>>(cnt, offs);
  k_fill   <<<E_/256, 256, 0, stream>>>(src, dst, ew, dis, offs, fillc, csrc, cwn);
  k_prep_cheb <<<6, 256, 0, stream>>>(cw, Bp);
  k_prep_conv2<<<12, 256, 0, stream>>>(w2, Bp2);

  // stage 1: temporal conv1 + GLU -> t0 (bf16)
  k_conv1<<<(G_*N_)/4, 256, 0, stream>>>(X, w1, b1, t0);

  // tx1 = L t0
  k_spmm<<<(G_*N_)/4, 256, 0, stream>>>(t0, nullptr, tx1, offs, csrc, cwn, 1.f);

  // tx2 = 2 L tx1 - t0
  k_spmm<<<(G_*N_)/4, 256, 0, stream>>>(tx1, t0, tx2, offs, csrc, cwn, 2.f);

  // tg = relu(bias + [t0|tx1|tx2] @ Wcat)   (MFMA)
  k_cheb_mfma<<<(G_*N_)/128, 256, 0, stream>>>(t0, tx1, tx2, Bp, cb, tg);

  // stage 3: temporal conv2 + GLU -> out   (MFMA)
  k_conv2_mfma<<<(B_*T2_)*16, 256, 0, stream>>>(tg, Bp2, b2, out);
}

// Round 4
// 250.302 us; speedup vs baseline: 10.8699x; 1.9540x over previous
//
#include <hip/hip_runtime.h>
#include <cstdint>

#define B_ 8
#define T_ 16
#define N_ 2048
#define CIN_ 2
#define H_ 64
#define COUT_ 64
#define KT_ 3
#define E_ 32768
#define T1_ 14
#define T2_ 12
#define G_ (B_*T1_)   // 112 graphs
#define GS_ (G_*H_)   // 7168: per-node stride in interleaved layout

typedef __attribute__((ext_vector_type(8))) short bf16x8;
typedef __attribute__((ext_vector_type(4))) float f32x4;
typedef unsigned short ushort_;
typedef __attribute__((ext_vector_type(4))) unsigned short u16x4;

__device__ __forceinline__ float sigmoidf_(float x){ return 1.f/(1.f+expf(-x)); }
__device__ __forceinline__ int rfl_(int x){ return __builtin_amdgcn_readfirstlane(x); }

__device__ __forceinline__ ushort_ f2b(float x){
  union {float f; uint32_t u;} v; v.f = x;
  uint32_t r = (v.u + 0x7FFFu + ((v.u>>16)&1u)) >> 16;
  return (ushort_)r;
}
__device__ __forceinline__ float b2f(ushort_ x){
  union {uint32_t u; float f;} v; v.u = ((uint32_t)x)<<16;
  return v.f;
}

// ---------------- CSR build ----------------
__global__ void k_deg_cnt(const int* __restrict__ src, const int* __restrict__ dst,
                          const float* __restrict__ ew, float* deg, int* cnt){
  int e = blockIdx.x*blockDim.x + threadIdx.x;
  if(e >= E_) return;
  int s = src[e], d = dst[e];
  float w = (s==d) ? 0.f : ew[e];
  atomicAdd(&deg[s], w);
  atomicAdd(&cnt[d], 1);
}

__global__ void k_dis(const float* __restrict__ deg, float* __restrict__ dis){
  int n = blockIdx.x*blockDim.x + threadIdx.x;
  if(n >= N_) return;
  float dg = deg[n];
  dis[n] = dg > 0.f ? rsqrtf(dg) : 0.f;
}

__global__ void k_scan(const int* __restrict__ cnt, int* __restrict__ offs){
  __shared__ int sums[256];
  int tid = threadIdx.x;
  int base = tid*8;
  int loc[8]; int s = 0;
  #pragma unroll
  for(int j=0;j<8;j++){ loc[j]=s; s += cnt[base+j]; }
  sums[tid] = s; __syncthreads();
  for(int ofs=1; ofs<256; ofs<<=1){
    int t = (tid>=ofs) ? sums[tid-ofs] : 0;
    __syncthreads();
    sums[tid] += t;
    __syncthreads();
  }
  int ebase = (tid==0) ? 0 : sums[tid-1];
  #pragma unroll
  for(int j=0;j<8;j++) offs[base+j] = ebase + loc[j];
  if(tid==255) offs[N_] = sums[255];
}

__global__ void k_fill(const int* __restrict__ src, const int* __restrict__ dst,
                       const float* __restrict__ ew, const float* __restrict__ dis,
                       const int* __restrict__ offs, int* fillc,
                       int2* __restrict__ epack){
  int e = blockIdx.x*blockDim.x + threadIdx.x;
  if(e >= E_) return;
  int s = src[e], d = dst[e];
  float w = (s==d) ? 0.f : ew[e];
  float wn = -dis[s]*w*dis[d];
  int pos = offs[d] + atomicAdd(&fillc[d], 1);
  epack[pos] = make_int2(s, __float_as_int(wn));
}

// ---- weight prepack into MFMA B-fragment layout (bf16) ----
__global__ void k_prep_cheb(const float* __restrict__ cw, ushort_* __restrict__ Bp){
  int i = blockIdx.x*blockDim.x + threadIdx.x;
  if(i >= 6*4*64) return;
  int lane = i & 63; int cn = i >> 6; int c = cn >> 2; int n = cn & 3;
  #pragma unroll
  for(int j=0;j<8;j++){
    int k = c*32 + (lane>>4)*8 + j;
    int col = n*16 + (lane&15);
    Bp[(size_t)i*8 + j] = f2b(cw[(size_t)k*64 + col]);
  }
}
__global__ void k_prep_conv2(const float* __restrict__ w2, ushort_* __restrict__ Bp2){
  int i = blockIdx.x*blockDim.x + threadIdx.x;
  if(i >= 6*8*64) return;
  int lane = i & 63; int cn = i >> 6; int c = cn >> 3; int n = cn & 7;
  #pragma unroll
  for(int j=0;j<8;j++){
    int k = c*32 + (lane>>4)*8 + j;
    int co = n*16 + (lane&15);
    int kt = k >> 6, ci = k & 63;
    Bp2[(size_t)i*8 + j] = f2b(w2[(size_t)co*192 + ci*3 + kt]);
  }
}

// ---------------- temporal conv 1 + GLU -> bf16, interleaved [n][g][c] ----------------
__global__ void k_conv1(const float* __restrict__ X, const float* __restrict__ w1,
                        const float* __restrict__ b1, ushort_* __restrict__ t0){
  int wv = rfl_(blockIdx.x*4 + (threadIdx.x>>6));
  int lane = threadIdx.x & 63;
  int n = wv % N_; int bt = wv / N_; int b = bt / T1_; int t = bt % T1_;
  const float* Xp = X + ((size_t)((b*T_ + t)*N_ + n))*CIN_;
  float xv[KT_*CIN_];
  #pragma unroll
  for(int kt=0;kt<KT_;kt++)
    #pragma unroll
    for(int ci=0;ci<CIN_;ci++)
      xv[kt*CIN_+ci] = Xp[kt*(N_*CIN_) + ci];
  float yp = b1[lane], yq = b1[lane+H_];
  #pragma unroll
  for(int ci=0;ci<CIN_;ci++)
    #pragma unroll
    for(int kt=0;kt<KT_;kt++){
      float x = xv[kt*CIN_+ci];
      yp += x * w1[ lane      *(CIN_*KT_) + ci*KT_ + kt];
      yq += x * w1[(lane+H_)*(CIN_*KT_) + ci*KT_ + kt];
    }
  float xin = (lane < CIN_) ? Xp[2*(N_*CIN_) + lane] : 0.f;
  t0[(size_t)n*GS_ + (size_t)bt*H_ + lane] = f2b((yp + xin) * sigmoidf_(yq));
}

// ---------------- SpMM interleaved: 4 graphs per wave, ushort4 gathers ----------------
// blockIdx = gg*512 + dblk; wave wv handles d = dblk*4+wv, graphs g0..g0+3
__global__ void k_spmm2(const ushort_* __restrict__ zin, const ushort_* __restrict__ sub,
                        ushort_* __restrict__ out, const int* __restrict__ offs,
                        const int2* __restrict__ epack, float scale){
  int lane = threadIdx.x & 63;
  int wv = threadIdx.x >> 6;
  int gg = blockIdx.x >> 9;          // 0..27
  int dblk = blockIdx.x & 511;
  int d = dblk*4 + wv;
  int g0 = gg*4;
  int e0 = offs[d], e1 = offs[d+1];
  size_t lo = (size_t)g0*H_ + lane*4;
  const ushort_* zb = zin + lo;
  float ac0=0.f, ac1=0.f, ac2=0.f, ac3=0.f;
  #pragma unroll 2
  for(int i=e0;i<e1;i++){
    int2 e = epack[i];
    float w = __int_as_float(e.y);
    u16x4 zv = *(const u16x4*)(zb + (size_t)e.x*GS_);
    ac0 += w*b2f(zv[0]); ac1 += w*b2f(zv[1]);
    ac2 += w*b2f(zv[2]); ac3 += w*b2f(zv[3]);
  }
  float v0 = scale*ac0, v1 = scale*ac1, v2 = scale*ac2, v3 = scale*ac3;
  size_t ob = (size_t)d*GS_ + lo;
  if(sub){
    u16x4 sv = *(const u16x4*)(sub + ob);
    v0 -= b2f(sv[0]); v1 -= b2f(sv[1]); v2 -= b2f(sv[2]); v3 -= b2f(sv[3]);
  }
  u16x4 ov; ov[0]=f2b(v0); ov[1]=f2b(v1); ov[2]=f2b(v2); ov[3]=f2b(v3);
  *(u16x4*)(out + ob) = ov;
}

// ---------------- cheb fused GEMM via MFMA (interleaved A) ----------------
// tg = relu(bias + [t0|tx1|tx2] @ Wcat); per graph g, rows n. tg stays flat [g*N+n][c].
__global__ void k_cheb_mfma(const ushort_* __restrict__ t0, const ushort_* __restrict__ tx1,
                            const ushort_* __restrict__ tx2, const ushort_* __restrict__ Bp,
                            const float* __restrict__ bias, ushort_* __restrict__ tg){
  int lane = threadIdx.x & 63;
  int wv = threadIdx.x >> 6;
  int g = blockIdx.x >> 4;
  int row0 = (blockIdx.x & 15)*128 + wv*32;
  int ra = row0 + (lane&15);
  f32x4 acc[2][4] = {};
  #pragma unroll
  for(int c=0;c<6;c++){
    const ushort_* s = (c>>1)==0 ? t0 : ((c>>1)==1 ? tx1 : tx2);
    int eoff = (c&1)*32 + (lane>>4)*8;
    const ushort_* sb = s + (size_t)g*H_ + eoff;
    bf16x8 a0 = *(const bf16x8*)(sb + (size_t)ra*GS_);
    bf16x8 a1 = *(const bf16x8*)(sb + (size_t)(ra+16)*GS_);
    #pragma unroll
    for(int n=0;n<4;n++){
      bf16x8 bfr = *(const bf16x8*)(Bp + ((size_t)(c*4+n)*64 + lane)*8);
      acc[0][n] = __builtin_amdgcn_mfma_f32_16x16x32_bf16(a0, bfr, acc[0][n], 0,0,0);
      acc[1][n] = __builtin_amdgcn_mfma_f32_16x16x32_bf16(a1, bfr, acc[1][n], 0,0,0);
    }
  }
  #pragma unroll
  for(int rg=0; rg<2; rg++)
    #pragma unroll
    for(int n=0;n<4;n++){
      int col = n*16 + (lane&15);
      float bv = bias[col];
      #pragma unroll
      for(int r=0;r<4;r++){
        int row = row0 + rg*16 + (lane>>4)*4 + r;
        float v = fmaxf(acc[rg][n][r] + bv, 0.f);
        tg[(size_t)(g*N_+row)*H_ + col] = f2b(v);
      }
    }
}

// ---------------- conv2 via MFMA ----------------
__global__ void k_conv2_mfma(const ushort_* __restrict__ tg, const ushort_* __restrict__ Bp2,
                             const float* __restrict__ b2, float* __restrict__ out){
  int lane = threadIdx.x & 63;
  int wv = threadIdx.x >> 6;
  int blk = blockIdx.x;          // 96*16
  int bt = blk >> 4; int nblk = blk & 15;
  int b = bt / T2_, t = bt % T2_;
  int n0 = nblk*128 + wv*32;
  const ushort_* base = tg + (size_t)(b*T1_ + t)*N_*H_;
  f32x4 acc[2][8] = {};
  #pragma unroll
  for(int c=0;c<6;c++){
    const ushort_* s = base + (size_t)(c>>1)*N_*H_;
    int eoff = (c&1)*32 + (lane>>4)*8;
    bf16x8 a0 = *(const bf16x8*)(s + (size_t)(n0 +      (lane&15))*H_ + eoff);
    bf16x8 a1 = *(const bf16x8*)(s + (size_t)(n0 + 16 + (lane&15))*H_ + eoff);
    #pragma unroll
    for(int n=0;n<8;n++){
      bf16x8 bfr = *(const bf16x8*)(Bp2 + ((size_t)(c*8+n)*64 + lane)*8);
      acc[0][n] = __builtin_amdgcn_mfma_f32_16x16x32_bf16(a0, bfr, acc[0][n], 0,0,0);
      acc[1][n] = __builtin_amdgcn_mfma_f32_16x16x32_bf16(a1, bfr, acc[1][n], 0,0,0);
    }
  }
  const ushort_* xslab = base + (size_t)2*N_*H_;
  float* ob = out + (size_t)(b*T2_ + t)*N_*H_;
  #pragma unroll
  for(int rg=0;rg<2;rg++)
    #pragma unroll
    for(int n=0;n<4;n++){
      int col = n*16 + (lane&15);
      float bp = b2[col], bq = b2[col+COUT_];
      #pragma unroll
      for(int r=0;r<4;r++){
        int row = n0 + rg*16 + (lane>>4)*4 + r;
        float xin = b2f(xslab[(size_t)row*H_ + col]);
        float p = acc[rg][n][r] + bp + xin;
        float q = acc[rg][n+4][r] + bq;
        ob[(size_t)row*H_ + col] = p * sigmoidf_(q);
      }
    }
}

extern "C" void kernel_launch(void* const* d_in, const int* in_sizes, int n_in,
                              void* d_out, int out_size, void* d_ws, size_t ws_size,
                              hipStream_t stream){
  (void)in_sizes; (void)n_in; (void)out_size; (void)ws_size;
  const float* X  = (const float*)d_in[0];
  const int*   ei = (const int*)d_in[1];
  const float* ew = (const float*)d_in[2];
  const float* w1 = (const float*)d_in[3];
  const float* b1 = (const float*)d_in[4];
  const float* cw = (const float*)d_in[5];
  const float* cb = (const float*)d_in[6];
  const float* w2 = (const float*)d_in[7];
  const float* b2 = (const float*)d_in[8];
  float* out = (float*)d_out;

  char* ws = (char*)d_ws;
  const size_t BUF = (size_t)G_*N_*H_*sizeof(ushort_); // 29,360,128 B
  ushort_* t0  = (ushort_*)(ws);
  ushort_* tx1 = (ushort_*)(ws + BUF);
  ushort_* tx2 = (ushort_*)(ws + 2*BUF);
  ushort_* tg  = (ushort_*)(ws + 3*BUF);
  char* sm = ws + 4*BUF;
  float* deg   = (float*)(sm);               // 8192
  float* dis   = (float*)(sm + 8192);        // 8192
  int*   cnt   = (int*)  (sm + 16384);       // 8192
  int*   fillc = (int*)  (sm + 24576);       // 8192
  int*   offs  = (int*)  (sm + 32768);       // 8448
  int2*  epack = (int2*) (sm + 41216);       // 262144
  ushort_* Bp  = (ushort_*)(sm + 41216 + 262144);          // 24576
  ushort_* Bp2 = (ushort_*)(sm + 41216 + 262144 + 24576);  // 49152

  const int* src = ei;
  const int* dst = ei + E_;

  hipMemsetAsync(deg,   0, 8192, stream);
  hipMemsetAsync(cnt,   0, 8192, stream);
  hipMemsetAsync(fillc, 0, 8192, stream);

  k_deg_cnt<<<E_/256, 256, 0, stream>>>(src, dst, ew, deg, cnt);
  k_dis    <<<N_/256, 256, 0, stream>>>(deg, dis);
  k_scan   <<<1,      256, 0, stream>>>(cnt, offs);
  k_fill   <<<E_/256, 256, 0, stream>>>(src, dst, ew, dis, offs, fillc, epack);
  k_prep_cheb <<<6, 256, 0, stream>>>(cw, Bp);
  k_prep_conv2<<<12, 256, 0, stream>>>(w2, Bp2);

  // stage 1: temporal conv1 + GLU -> t0 (bf16, interleaved)
  k_conv1<<<(G_*N_)/4, 256, 0, stream>>>(X, w1, b1, t0);

  // tx1 = L t0
  k_spmm2<<<28*512, 256, 0, stream>>>(t0, nullptr, tx1, offs, epack, 1.f);

  // tx2 = 2 L tx1 - t0
  k_spmm2<<<28*512, 256, 0, stream>>>(tx1, t0, tx2, offs, epack, 2.f);

  // tg = relu(bias + [t0|tx1|tx2] @ Wcat)   (MFMA)
  k_cheb_mfma<<<G_*16, 256, 0, stream>>>(t0, tx1, tx2, Bp, cb, tg);

  // stage 3: temporal conv2 + GLU -> out   (MFMA)
  k_conv2_mfma<<<(B_*T2_)*16, 256, 0, stream>>>(tg, Bp2, b2, out);
}

// Round 5
// 195.361 us; speedup vs baseline: 13.9269x; 1.2812x over previous
//
#include <hip/hip_runtime.h>
#include <cstdint>

#define B_ 8
#define T_ 16
#define N_ 2048
#define CIN_ 2
#define H_ 64
#define COUT_ 64
#define KT_ 3
#define E_ 32768
#define T1_ 14
#define T2_ 12
#define G_ (B_*T1_)   // 112 graphs
#define GS_ (G_*H_)   // 7168: per-node stride in interleaved layout

typedef __attribute__((ext_vector_type(8))) short bf16x8;
typedef __attribute__((ext_vector_type(4))) float f32x4;
typedef unsigned short ushort_;
typedef __attribute__((ext_vector_type(8))) unsigned short u16x8;

__device__ __forceinline__ float sigmoidf_(float x){ return 1.f/(1.f+expf(-x)); }
__device__ __forceinline__ int rfl_(int x){ return __builtin_amdgcn_readfirstlane(x); }

__device__ __forceinline__ ushort_ f2b(float x){
  union {float f; uint32_t u;} v; v.f = x;
  uint32_t r = (v.u + 0x7FFFu + ((v.u>>16)&1u)) >> 16;
  return (ushort_)r;
}
__device__ __forceinline__ float b2f(ushort_ x){
  union {uint32_t u; float f;} v; v.u = ((uint32_t)x)<<16;
  return v.f;
}

// ---------------- CSR build ----------------
__global__ void k_deg_cnt(const int* __restrict__ src, const int* __restrict__ dst,
                          const float* __restrict__ ew, float* deg, int* cnt){
  int e = blockIdx.x*blockDim.x + threadIdx.x;
  if(e >= E_) return;
  int s = src[e], d = dst[e];
  float w = (s==d) ? 0.f : ew[e];
  atomicAdd(&deg[s], w);
  atomicAdd(&cnt[d], 1);
}

__global__ void k_dis(const float* __restrict__ deg, float* __restrict__ dis){
  int n = blockIdx.x*blockDim.x + threadIdx.x;
  if(n >= N_) return;
  float dg = deg[n];
  dis[n] = dg > 0.f ? rsqrtf(dg) : 0.f;
}

__global__ void k_scan(const int* __restrict__ cnt, int* __restrict__ offs){
  __shared__ int sums[256];
  int tid = threadIdx.x;
  int base = tid*8;
  int loc[8]; int s = 0;
  #pragma unroll
  for(int j=0;j<8;j++){ loc[j]=s; s += cnt[base+j]; }
  sums[tid] = s; __syncthreads();
  for(int ofs=1; ofs<256; ofs<<=1){
    int t = (tid>=ofs) ? sums[tid-ofs] : 0;
    __syncthreads();
    sums[tid] += t;
    __syncthreads();
  }
  int ebase = (tid==0) ? 0 : sums[tid-1];
  #pragma unroll
  for(int j=0;j<8;j++) offs[base+j] = ebase + loc[j];
  if(tid==255) offs[N_] = sums[255];
}

__global__ void k_fill(const int* __restrict__ src, const int* __restrict__ dst,
                       const float* __restrict__ ew, const float* __restrict__ dis,
                       const int* __restrict__ offs, int* fillc,
                       int2* __restrict__ epack){
  int e = blockIdx.x*blockDim.x + threadIdx.x;
  if(e >= E_) return;
  int s = src[e], d = dst[e];
  float w = (s==d) ? 0.f : ew[e];
  float wn = -dis[s]*w*dis[d];
  int pos = offs[d] + atomicAdd(&fillc[d], 1);
  epack[pos] = make_int2(s, __float_as_int(wn));
}

// ---- weight prepack into MFMA B-fragment layout (bf16) ----
// chunk c -> m=c>>1; baked: m=0 -> W0-W2, m=1 -> W1, m=2 -> 2*W2
__global__ void k_prep_cheb(const float* __restrict__ cw, ushort_* __restrict__ Bp){
  int i = blockIdx.x*blockDim.x + threadIdx.x;
  if(i >= 6*4*64) return;
  int lane = i & 63; int cn = i >> 6; int c = cn >> 2; int n = cn & 3;
  #pragma unroll
  for(int j=0;j<8;j++){
    int k = c*32 + (lane>>4)*8 + j;   // 0..191
    int h = k & 63; int m = k >> 6;
    int col = n*16 + (lane&15);
    float v;
    if(m == 0)      v = cw[(size_t)h*64 + col] - cw[(size_t)(128+h)*64 + col];
    else if(m == 1) v = cw[(size_t)(64+h)*64 + col];
    else            v = 2.f*cw[(size_t)(128+h)*64 + col];
    Bp[(size_t)i*8 + j] = f2b(v);
  }
}
__global__ void k_prep_conv2(const float* __restrict__ w2, ushort_* __restrict__ Bp2){
  int i = blockIdx.x*blockDim.x + threadIdx.x;
  if(i >= 6*8*64) return;
  int lane = i & 63; int cn = i >> 6; int c = cn >> 3; int n = cn & 7;
  #pragma unroll
  for(int j=0;j<8;j++){
    int k = c*32 + (lane>>4)*8 + j;
    int co = n*16 + (lane&15);
    int kt = k >> 6, ci = k & 63;
    Bp2[(size_t)i*8 + j] = f2b(w2[(size_t)co*192 + ci*3 + kt]);
  }
}

// ---------------- temporal conv 1 + GLU -> bf16, interleaved [n][g][c] ----------------
__global__ void k_conv1(const float* __restrict__ X, const float* __restrict__ w1,
                        const float* __restrict__ b1, ushort_* __restrict__ t0){
  int wv = rfl_(blockIdx.x*4 + (threadIdx.x>>6));
  int lane = threadIdx.x & 63;
  int n = wv % N_; int bt = wv / N_; int b = bt / T1_; int t = bt % T1_;
  const float* Xp = X + ((size_t)((b*T_ + t)*N_ + n))*CIN_;
  float xv[KT_*CIN_];
  #pragma unroll
  for(int kt=0;kt<KT_;kt++)
    #pragma unroll
    for(int ci=0;ci<CIN_;ci++)
      xv[kt*CIN_+ci] = Xp[kt*(N_*CIN_) + ci];
  float yp = b1[lane], yq = b1[lane+H_];
  #pragma unroll
  for(int ci=0;ci<CIN_;ci++)
    #pragma unroll
    for(int kt=0;kt<KT_;kt++){
      float x = xv[kt*CIN_+ci];
      yp += x * w1[ lane      *(CIN_*KT_) + ci*KT_ + kt];
      yq += x * w1[(lane+H_)*(CIN_*KT_) + ci*KT_ + kt];
    }
  float xin = (lane < CIN_) ? Xp[2*(N_*CIN_) + lane] : 0.f;
  t0[(size_t)n*GS_ + (size_t)bt*H_ + lane] = f2b((yp + xin) * sigmoidf_(yq));
}

// ---------------- SpMM interleaved: out = L zin. 8 graphs/wave, 16B gathers, XCD-swizzled ----
// work = (bid&7)*(nwg/8) + bid>>3 ; gg = work>>9 (0..13), dblk = work&511; d = dblk*4+wv
__global__ void k_spmm3(const ushort_* __restrict__ zin, ushort_* __restrict__ out,
                        const int* __restrict__ offs, const int2* __restrict__ epack){
  int lane = threadIdx.x & 63;
  int wv = threadIdx.x >> 6;
  int bid = blockIdx.x;                 // 14*512 = 7168
  int work = (bid & 7)*896 + (bid >> 3);
  int gg = work >> 9;                   // 0..13
  int dblk = work & 511;
  int d = dblk*4 + wv;
  int e0 = offs[d], e1 = offs[d+1];
  size_t lo = (size_t)(gg*8)*H_ + lane*8;
  const ushort_* zb = zin + lo;
  float ac[8] = {};
  #pragma unroll 2
  for(int i=e0;i<e1;i++){
    int2 e = epack[i];
    float w = __int_as_float(e.y);
    u16x8 zv = *(const u16x8*)(zb + (size_t)e.x*GS_);
    #pragma unroll
    for(int j=0;j<8;j++) ac[j] += w*b2f(zv[j]);
  }
  u16x8 ov;
  #pragma unroll
  for(int j=0;j<8;j++) ov[j] = f2b(ac[j]);
  *(u16x8*)(out + (size_t)d*GS_ + lo) = ov;
}

// ---------------- cheb fused GEMM via MFMA (interleaved A) ----------------
// tg = relu(bias + t0*(W0-W2) + tx1*W1 + y2*(2W2)); weights pre-baked in Bp.
__global__ void k_cheb_mfma(const ushort_* __restrict__ t0, const ushort_* __restrict__ tx1,
                            const ushort_* __restrict__ y2, const ushort_* __restrict__ Bp,
                            const float* __restrict__ bias, ushort_* __restrict__ tg){
  int lane = threadIdx.x & 63;
  int wv = threadIdx.x >> 6;
  int g = blockIdx.x >> 4;
  int row0 = (blockIdx.x & 15)*128 + wv*32;
  int ra = row0 + (lane&15);
  f32x4 acc[2][4] = {};
  #pragma unroll
  for(int c=0;c<6;c++){
    const ushort_* s = (c>>1)==0 ? t0 : ((c>>1)==1 ? tx1 : y2);
    int eoff = (c&1)*32 + (lane>>4)*8;
    const ushort_* sb = s + (size_t)g*H_ + eoff;
    bf16x8 a0 = *(const bf16x8*)(sb + (size_t)ra*GS_);
    bf16x8 a1 = *(const bf16x8*)(sb + (size_t)(ra+16)*GS_);
    #pragma unroll
    for(int n=0;n<4;n++){
      bf16x8 bfr = *(const bf16x8*)(Bp + ((size_t)(c*4+n)*64 + lane)*8);
      acc[0][n] = __builtin_amdgcn_mfma_f32_16x16x32_bf16(a0, bfr, acc[0][n], 0,0,0);
      acc[1][n] = __builtin_amdgcn_mfma_f32_16x16x32_bf16(a1, bfr, acc[1][n], 0,0,0);
    }
  }
  #pragma unroll
  for(int rg=0; rg<2; rg++)
    #pragma unroll
    for(int n=0;n<4;n++){
      int col = n*16 + (lane&15);
      float bv = bias[col];
      #pragma unroll
      for(int r=0;r<4;r++){
        int row = row0 + rg*16 + (lane>>4)*4 + r;
        float v = fmaxf(acc[rg][n][r] + bv, 0.f);
        tg[(size_t)(g*N_+row)*H_ + col] = f2b(v);
      }
    }
}

// ---------------- conv2 via MFMA ----------------
__global__ void k_conv2_mfma(const ushort_* __restrict__ tg, const ushort_* __restrict__ Bp2,
                             const float* __restrict__ b2, float* __restrict__ out){
  int lane = threadIdx.x & 63;
  int wv = threadIdx.x >> 6;
  int blk = blockIdx.x;          // 96*16
  int bt = blk >> 4; int nblk = blk & 15;
  int b = bt / T2_, t = bt % T2_;
  int n0 = nblk*128 + wv*32;
  const ushort_* base = tg + (size_t)(b*T1_ + t)*N_*H_;
  f32x4 acc[2][8] = {};
  #pragma unroll
  for(int c=0;c<6;c++){
    const ushort_* s = base + (size_t)(c>>1)*N_*H_;
    int eoff = (c&1)*32 + (lane>>4)*8;
    bf16x8 a0 = *(const bf16x8*)(s + (size_t)(n0 +      (lane&15))*H_ + eoff);
    bf16x8 a1 = *(const bf16x8*)(s + (size_t)(n0 + 16 + (lane&15))*H_ + eoff);
    #pragma unroll
    for(int n=0;n<8;n++){
      bf16x8 bfr = *(const bf16x8*)(Bp2 + ((size_t)(c*8+n)*64 + lane)*8);
      acc[0][n] = __builtin_amdgcn_mfma_f32_16x16x32_bf16(a0, bfr, acc[0][n], 0,0,0);
      acc[1][n] = __builtin_amdgcn_mfma_f32_16x16x32_bf16(a1, bfr, acc[1][n], 0,0,0);
    }
  }
  const ushort_* xslab = base + (size_t)2*N_*H_;
  float* ob = out + (size_t)(b*T2_ + t)*N_*H_;
  #pragma unroll
  for(int rg=0;rg<2;rg++)
    #pragma unroll
    for(int n=0;n<4;n++){
      int col = n*16 + (lane&15);
      float bp = b2[col], bq = b2[col+COUT_];
      #pragma unroll
      for(int r=0;r<4;r++){
        int row = n0 + rg*16 + (lane>>4)*4 + r;
        float xin = b2f(xslab[(size_t)row*H_ + col]);
        float p = acc[rg][n][r] + bp + xin;
        float q = acc[rg][n+4][r] + bq;
        ob[(size_t)row*H_ + col] = p * sigmoidf_(q);
      }
    }
}

extern "C" void kernel_launch(void* const* d_in, const int* in_sizes, int n_in,
                              void* d_out, int out_size, void* d_ws, size_t ws_size,
                              hipStream_t stream){
  (void)in_sizes; (void)n_in; (void)out_size; (void)ws_size;
  const float* X  = (const float*)d_in[0];
  const int*   ei = (const int*)d_in[1];
  const float* ew = (const float*)d_in[2];
  const float* w1 = (const float*)d_in[3];
  const float* b1 = (const float*)d_in[4];
  const float* cw = (const float*)d_in[5];
  const float* cb = (const float*)d_in[6];
  const float* w2 = (const float*)d_in[7];
  const float* b2 = (const float*)d_in[8];
  float* out = (float*)d_out;

  char* ws = (char*)d_ws;
  const size_t BUF = (size_t)G_*N_*H_*sizeof(ushort_); // 29,360,128 B
  ushort_* t0  = (ushort_*)(ws);
  ushort_* tx1 = (ushort_*)(ws + BUF);
  ushort_* y2  = (ushort_*)(ws + 2*BUF);
  ushort_* tg  = (ushort_*)(ws + 3*BUF);
  char* sm = ws + 4*BUF;
  float* deg   = (float*)(sm);               // 8192
  float* dis   = (float*)(sm + 8192);        // 8192
  int*   cnt   = (int*)  (sm + 16384);       // 8192
  int*   fillc = (int*)  (sm + 24576);       // 8192
  int*   offs  = (int*)  (sm + 32768);       // 8448
  int2*  epack = (int2*) (sm + 41216);       // 262144
  ushort_* Bp  = (ushort_*)(sm + 41216 + 262144);          // 24576
  ushort_* Bp2 = (ushort_*)(sm + 41216 + 262144 + 24576);  // 49152

  const int* src = ei;
  const int* dst = ei + E_;

  hipMemsetAsync(deg,   0, 8192, stream);
  hipMemsetAsync(cnt,   0, 8192, stream);
  hipMemsetAsync(fillc, 0, 8192, stream);

  k_deg_cnt<<<E_/256, 256, 0, stream>>>(src, dst, ew, deg, cnt);
  k_dis    <<<N_/256, 256, 0, stream>>>(deg, dis);
  k_scan   <<<1,      256, 0, stream>>>(cnt, offs);
  k_fill   <<<E_/256, 256, 0, stream>>>(src, dst, ew, dis, offs, fillc, epack);
  k_prep_cheb <<<6, 256, 0, stream>>>(cw, Bp);
  k_prep_conv2<<<12, 256, 0, stream>>>(w2, Bp2);

  // stage 1: temporal conv1 + GLU -> t0 (bf16, interleaved)
  k_conv1<<<(G_*N_)/4, 256, 0, stream>>>(X, w1, b1, t0);

  // tx1 = L t0 ; y2 = L tx1
  k_spmm3<<<14*512, 256, 0, stream>>>(t0,  tx1, offs, epack);
  k_spmm3<<<14*512, 256, 0, stream>>>(tx1, y2,  offs, epack);

  // tg = relu(bias + t0*(W0-W2) + tx1*W1 + y2*(2W2))   (MFMA, baked weights)
  k_cheb_mfma<<<G_*16, 256, 0, stream>>>(t0, tx1, y2, Bp, cb, tg);

  // stage 3: temporal conv2 + GLU -> out   (MFMA)
  k_conv2_mfma<<<(B_*T2_)*16, 256, 0, stream>>>(tg, Bp2, b2, out);
}

// Round 6
// 195.271 us; speedup vs baseline: 13.9333x; 1.0005x over previous
//
#include <hip/hip_runtime.h>
#include <cstdint>

#define B_ 8
#define T_ 16
#define N_ 2048
#define CIN_ 2
#define H_ 64
#define COUT_ 64
#define KT_ 3
#define E_ 32768
#define T1_ 14
#define T2_ 12
#define G_ (B_*T1_)   // 112 graphs
#define GS_ (G_*H_)   // 7168: per-node stride in interleaved layout

typedef __attribute__((ext_vector_type(8))) short bf16x8;
typedef __attribute__((ext_vector_type(4))) float f32x4;
typedef unsigned short ushort_;
typedef __attribute__((ext_vector_type(8))) unsigned short u16x8;

__device__ __forceinline__ float sigmoidf_(float x){ return 1.f/(1.f+expf(-x)); }
__device__ __forceinline__ int rfl_(int x){ return __builtin_amdgcn_readfirstlane(x); }

__device__ __forceinline__ ushort_ f2b(float x){
  union {float f; uint32_t u;} v; v.f = x;
  uint32_t r = (v.u + 0x7FFFu + ((v.u>>16)&1u)) >> 16;
  return (ushort_)r;
}
__device__ __forceinline__ float b2f(ushort_ x){
  union {uint32_t u; float f;} v; v.u = ((uint32_t)x)<<16;
  return v.f;
}

// ---------------- CSR build ----------------
__global__ void k_deg_cnt(const int* __restrict__ src, const int* __restrict__ dst,
                          const float* __restrict__ ew, float* deg, int* cnt){
  int e = blockIdx.x*blockDim.x + threadIdx.x;
  if(e >= E_) return;
  int s = src[e], d = dst[e];
  float w = (s==d) ? 0.f : ew[e];
  atomicAdd(&deg[s], w);
  atomicAdd(&cnt[d], 1);
}

__global__ void k_dis(const float* __restrict__ deg, float* __restrict__ dis){
  int n = blockIdx.x*blockDim.x + threadIdx.x;
  if(n >= N_) return;
  float dg = deg[n];
  dis[n] = dg > 0.f ? rsqrtf(dg) : 0.f;
}

__global__ void k_scan(const int* __restrict__ cnt, int* __restrict__ offs){
  __shared__ int sums[256];
  int tid = threadIdx.x;
  int base = tid*8;
  int loc[8]; int s = 0;
  #pragma unroll
  for(int j=0;j<8;j++){ loc[j]=s; s += cnt[base+j]; }
  sums[tid] = s; __syncthreads();
  for(int ofs=1; ofs<256; ofs<<=1){
    int t = (tid>=ofs) ? sums[tid-ofs] : 0;
    __syncthreads();
    sums[tid] += t;
    __syncthreads();
  }
  int ebase = (tid==0) ? 0 : sums[tid-1];
  #pragma unroll
  for(int j=0;j<8;j++) offs[base+j] = ebase + loc[j];
  if(tid==255) offs[N_] = sums[255];
}

__global__ void k_fill(const int* __restrict__ src, const int* __restrict__ dst,
                       const float* __restrict__ ew, const float* __restrict__ dis,
                       const int* __restrict__ offs, int* fillc,
                       int2* __restrict__ epack){
  int e = blockIdx.x*blockDim.x + threadIdx.x;
  if(e >= E_) return;
  int s = src[e], d = dst[e];
  float w = (s==d) ? 0.f : ew[e];
  float wn = -dis[s]*w*dis[d];
  int pos = offs[d] + atomicAdd(&fillc[d], 1);
  epack[pos] = make_int2(s, __float_as_int(wn));
}

// ---- weight prepack into MFMA B-fragment layout (bf16) ----
// chunk c -> m=c>>1; baked: m=0 -> W0-W2, m=1 -> W1, m=2 -> 2*W2
__global__ void k_prep_cheb(const float* __restrict__ cw, ushort_* __restrict__ Bp){
  int i = blockIdx.x*blockDim.x + threadIdx.x;
  if(i >= 6*4*64) return;
  int lane = i & 63; int cn = i >> 6; int c = cn >> 2; int n = cn & 3;
  #pragma unroll
  for(int j=0;j<8;j++){
    int k = c*32 + (lane>>4)*8 + j;   // 0..191
    int h = k & 63; int m = k >> 6;
    int col = n*16 + (lane&15);
    float v;
    if(m == 0)      v = cw[(size_t)h*64 + col] - cw[(size_t)(128+h)*64 + col];
    else if(m == 1) v = cw[(size_t)(64+h)*64 + col];
    else            v = 2.f*cw[(size_t)(128+h)*64 + col];
    Bp[(size_t)i*8 + j] = f2b(v);
  }
}
__global__ void k_prep_conv2(const float* __restrict__ w2, ushort_* __restrict__ Bp2){
  int i = blockIdx.x*blockDim.x + threadIdx.x;
  if(i >= 6*8*64) return;
  int lane = i & 63; int cn = i >> 6; int c = cn >> 3; int n = cn & 7;
  #pragma unroll
  for(int j=0;j<8;j++){
    int k = c*32 + (lane>>4)*8 + j;
    int co = n*16 + (lane&15);
    int kt = k >> 6, ci = k & 63;
    Bp2[(size_t)i*8 + j] = f2b(w2[(size_t)co*192 + ci*3 + kt]);
  }
}

// ---------------- temporal conv 1 + GLU -> bf16, interleaved [n][g][c] ----------------
__global__ void k_conv1(const float* __restrict__ X, const float* __restrict__ w1,
                        const float* __restrict__ b1, ushort_* __restrict__ t0){
  int wv = rfl_(blockIdx.x*4 + (threadIdx.x>>6));
  int lane = threadIdx.x & 63;
  int n = wv % N_; int bt = wv / N_; int b = bt / T1_; int t = bt % T1_;
  const float* Xp = X + ((size_t)((b*T_ + t)*N_ + n))*CIN_;
  float xv[KT_*CIN_];
  #pragma unroll
  for(int kt=0;kt<KT_;kt++)
    #pragma unroll
    for(int ci=0;ci<CIN_;ci++)
      xv[kt*CIN_+ci] = Xp[kt*(N_*CIN_) + ci];
  float yp = b1[lane], yq = b1[lane+H_];
  #pragma unroll
  for(int ci=0;ci<CIN_;ci++)
    #pragma unroll
    for(int kt=0;kt<KT_;kt++){
      float x = xv[kt*CIN_+ci];
      yp += x * w1[ lane      *(CIN_*KT_) + ci*KT_ + kt];
      yq += x * w1[(lane+H_)*(CIN_*KT_) + ci*KT_ + kt];
    }
  float xin = (lane < CIN_) ? Xp[2*(N_*CIN_) + lane] : 0.f;
  t0[(size_t)n*GS_ + (size_t)bt*H_ + lane] = f2b((yp + xin) * sigmoidf_(yq));
}

// ---------------- SpMM interleaved: out = L zin. 8 graphs/wave, 16B gathers, XCD-swizzled ----
__global__ void k_spmm3(const ushort_* __restrict__ zin, ushort_* __restrict__ out,
                        const int* __restrict__ offs, const int2* __restrict__ epack){
  int lane = threadIdx.x & 63;
  int wv = threadIdx.x >> 6;
  int bid = blockIdx.x;                 // 14*512 = 7168
  int work = (bid & 7)*896 + (bid >> 3);
  int gg = work >> 9;                   // 0..13
  int dblk = work & 511;
  int d = dblk*4 + wv;
  int e0 = offs[d], e1 = offs[d+1];
  size_t lo = (size_t)(gg*8)*H_ + lane*8;
  const ushort_* zb = zin + lo;
  float ac[8] = {};
  #pragma unroll 2
  for(int i=e0;i<e1;i++){
    int2 e = epack[i];
    float w = __int_as_float(e.y);
    u16x8 zv = *(const u16x8*)(zb + (size_t)e.x*GS_);
    #pragma unroll
    for(int j=0;j<8;j++) ac[j] += w*b2f(zv[j]);
  }
  u16x8 ov;
  #pragma unroll
  for(int j=0;j<8;j++) ov[j] = f2b(ac[j]);
  *(u16x8*)(out + (size_t)d*GS_ + lo) = ov;
}

// ---------------- cheb fused GEMM via MFMA (interleaved A, hoisted loads) ----------------
// tg = relu(bias + t0*(W0-W2) + tx1*W1 + y2*(2W2)); weights pre-baked in Bp.
__global__ void k_cheb_mfma(const ushort_* __restrict__ t0, const ushort_* __restrict__ tx1,
                            const ushort_* __restrict__ y2, const ushort_* __restrict__ Bp,
                            const float* __restrict__ bias, ushort_* __restrict__ tg){
  int lane = threadIdx.x & 63;
  int wv = threadIdx.x >> 6;
  int g = blockIdx.x >> 4;
  int row0 = (blockIdx.x & 15)*128 + wv*32;
  int ra = row0 + (lane&15);
  // hoist all 12 A fragments (one latency exposure)
  bf16x8 a[2][6];
  #pragma unroll
  for(int c=0;c<6;c++){
    const ushort_* s = (c>>1)==0 ? t0 : ((c>>1)==1 ? tx1 : y2);
    int eoff = (c&1)*32 + (lane>>4)*8;
    const ushort_* sb = s + (size_t)g*H_ + eoff;
    a[0][c] = *(const bf16x8*)(sb + (size_t)ra*GS_);
    a[1][c] = *(const bf16x8*)(sb + (size_t)(ra+16)*GS_);
  }
  f32x4 acc[2][4] = {};
  #pragma unroll
  for(int c=0;c<6;c++){
    #pragma unroll
    for(int n=0;n<4;n++){
      bf16x8 bfr = *(const bf16x8*)(Bp + ((size_t)(c*4+n)*64 + lane)*8);
      acc[0][n] = __builtin_amdgcn_mfma_f32_16x16x32_bf16(a[0][c], bfr, acc[0][n], 0,0,0);
      acc[1][n] = __builtin_amdgcn_mfma_f32_16x16x32_bf16(a[1][c], bfr, acc[1][n], 0,0,0);
    }
  }
  #pragma unroll
  for(int rg=0; rg<2; rg++)
    #pragma unroll
    for(int n=0;n<4;n++){
      int col = n*16 + (lane&15);
      float bv = bias[col];
      #pragma unroll
      for(int r=0;r<4;r++){
        int row = row0 + rg*16 + (lane>>4)*4 + r;
        float v = fmaxf(acc[rg][n][r] + bv, 0.f);
        tg[(size_t)(g*N_+row)*H_ + col] = f2b(v);
      }
    }
}

// ---------------- conv2 via MFMA (hoisted A + xin, 16 rows/wave) ----------------
__global__ void k_conv2_mfma(const ushort_* __restrict__ tg, const ushort_* __restrict__ Bp2,
                             const float* __restrict__ b2, float* __restrict__ out){
  int lane = threadIdx.x & 63;
  int wv = threadIdx.x >> 6;
  int blk = blockIdx.x;          // 96*32
  int bt = blk >> 5; int nblk = blk & 31;
  int b = bt / T2_, t = bt % T2_;
  int n0 = nblk*64 + wv*16;
  const ushort_* base = tg + (size_t)(b*T1_ + t)*N_*H_;
  int ra = n0 + (lane&15);
  // hoist all 6 A fragments
  bf16x8 a[6];
  #pragma unroll
  for(int c=0;c<6;c++){
    const ushort_* s = base + (size_t)(c>>1)*N_*H_;
    int eoff = (c&1)*32 + (lane>>4)*8;
    a[c] = *(const bf16x8*)(s + (size_t)ra*H_ + eoff);
  }
  // hoist xin fragment (rows n0.., col pattern = C-fragment layout)
  const ushort_* xslab = base + (size_t)2*N_*H_;
  float xin[4][4];
  #pragma unroll
  for(int n=0;n<4;n++)
    #pragma unroll
    for(int r=0;r<4;r++){
      int row = n0 + (lane>>4)*4 + r;
      xin[n][r] = b2f(xslab[(size_t)row*H_ + n*16 + (lane&15)]);
    }
  f32x4 acc[8] = {};
  #pragma unroll
  for(int c=0;c<6;c++){
    #pragma unroll
    for(int n=0;n<8;n++){
      bf16x8 bfr = *(const bf16x8*)(Bp2 + ((size_t)(c*8+n)*64 + lane)*8);
      acc[n] = __builtin_amdgcn_mfma_f32_16x16x32_bf16(a[c], bfr, acc[n], 0,0,0);
    }
  }
  float* ob = out + (size_t)(b*T2_ + t)*N_*H_;
  #pragma unroll
  for(int n=0;n<4;n++){
    int col = n*16 + (lane&15);
    float bp = b2[col], bq = b2[col+COUT_];
    #pragma unroll
    for(int r=0;r<4;r++){
      int row = n0 + (lane>>4)*4 + r;
      float p = acc[n][r] + bp + xin[n][r];
      float q = acc[n+4][r] + bq;
      ob[(size_t)row*H_ + col] = p * sigmoidf_(q);
    }
  }
}

extern "C" void kernel_launch(void* const* d_in, const int* in_sizes, int n_in,
                              void* d_out, int out_size, void* d_ws, size_t ws_size,
                              hipStream_t stream){
  (void)in_sizes; (void)n_in; (void)out_size; (void)ws_size;
  const float* X  = (const float*)d_in[0];
  const int*   ei = (const int*)d_in[1];
  const float* ew = (const float*)d_in[2];
  const float* w1 = (const float*)d_in[3];
  const float* b1 = (const float*)d_in[4];
  const float* cw = (const float*)d_in[5];
  const float* cb = (const float*)d_in[6];
  const float* w2 = (const float*)d_in[7];
  const float* b2 = (const float*)d_in[8];
  float* out = (float*)d_out;

  char* ws = (char*)d_ws;
  const size_t BUF = (size_t)G_*N_*H_*sizeof(ushort_); // 29,360,128 B
  ushort_* t0  = (ushort_*)(ws);
  ushort_* tx1 = (ushort_*)(ws + BUF);
  ushort_* y2  = (ushort_*)(ws + 2*BUF);
  ushort_* tg  = (ushort_*)(ws + 3*BUF);
  char* sm = ws + 4*BUF;
  float* deg   = (float*)(sm);               // 8192
  float* dis   = (float*)(sm + 8192);        // 8192
  int*   cnt   = (int*)  (sm + 16384);       // 8192
  int*   fillc = (int*)  (sm + 24576);       // 8192
  int*   offs  = (int*)  (sm + 32768);       // 8448
  int2*  epack = (int2*) (sm + 41216);       // 262144
  ushort_* Bp  = (ushort_*)(sm + 41216 + 262144);          // 24576
  ushort_* Bp2 = (ushort_*)(sm + 41216 + 262144 + 24576);  // 49152

  const int* src = ei;
  const int* dst = ei + E_;

  hipMemsetAsync(deg,   0, 8192, stream);
  hipMemsetAsync(cnt,   0, 8192, stream);
  hipMemsetAsync(fillc, 0, 8192, stream);

  k_deg_cnt<<<E_/256, 256, 0, stream>>>(src, dst, ew, deg, cnt);
  k_dis    <<<N_/256, 256, 0, stream>>>(deg, dis);
  k_scan   <<<1,      256, 0, stream>>>(cnt, offs);
  k_fill   <<<E_/256, 256, 0, stream>>>(src, dst, ew, dis, offs, fillc, epack);
  k_prep_cheb <<<6, 256, 0, stream>>>(cw, Bp);
  k_prep_conv2<<<12, 256, 0, stream>>>(w2, Bp2);

  // stage 1: temporal conv1 + GLU -> t0 (bf16, interleaved)
  k_conv1<<<(G_*N_)/4, 256, 0, stream>>>(X, w1, b1, t0);

  // tx1 = L t0 ; y2 = L tx1
  k_spmm3<<<14*512, 256, 0, stream>>>(t0,  tx1, offs, epack);
  k_spmm3<<<14*512, 256, 0, stream>>>(tx1, y2,  offs, epack);

  // tg = relu(bias + t0*(W0-W2) + tx1*W1 + y2*(2W2))   (MFMA, baked weights)
  k_cheb_mfma<<<G_*16, 256, 0, stream>>>(t0, tx1, y2, Bp, cb, tg);

  // stage 3: temporal conv2 + GLU -> out   (MFMA)
  k_conv2_mfma<<<(B_*T2_)*32, 256, 0, stream>>>(tg, Bp2, b2, out);
}

// Round 7
// 160.013 us; speedup vs baseline: 17.0034x; 1.2203x over previous
//
#include <hip/hip_runtime.h>
#include <cstdint>

#define B_ 8
#define T_ 16
#define N_ 2048
#define CIN_ 2
#define H_ 64
#define COUT_ 64
#define KT_ 3
#define E_ 32768
#define T1_ 14
#define T2_ 12
#define G_ (B_*T1_)   // 112 graphs
#define GS_ (G_*H_)   // 7168: per-node stride in interleaved layout

typedef __attribute__((ext_vector_type(8))) short bf16x8;
typedef __attribute__((ext_vector_type(4))) float f32x4;
typedef unsigned short ushort_;
typedef __attribute__((ext_vector_type(8))) unsigned short u16x8;

__device__ __forceinline__ float sigmoidf_(float x){ return 1.f/(1.f+expf(-x)); }
__device__ __forceinline__ int rfl_(int x){ return __builtin_amdgcn_readfirstlane(x); }

__device__ __forceinline__ ushort_ f2b(float x){
  union {float f; uint32_t u;} v; v.f = x;
  uint32_t r = (v.u + 0x7FFFu + ((v.u>>16)&1u)) >> 16;
  return (ushort_)r;
}
__device__ __forceinline__ float b2f(ushort_ x){
  union {uint32_t u; float f;} v; v.u = ((uint32_t)x)<<16;
  return v.f;
}

// ---------------- init small buffers (replaces 3 memsets) ----------------
__global__ void k_zero(float* __restrict__ deg, int* __restrict__ cnt, int* __restrict__ fillc){
  int i = blockIdx.x*blockDim.x + threadIdx.x;
  if(i < N_){ deg[i] = 0.f; cnt[i] = 0; fillc[i] = 0; }
}

// ---------------- CSR build ----------------
__global__ void k_deg_cnt(const int* __restrict__ src, const int* __restrict__ dst,
                          const float* __restrict__ ew, float* deg, int* cnt){
  int e = blockIdx.x*blockDim.x + threadIdx.x;
  if(e >= E_) return;
  int s = src[e], d = dst[e];
  float w = (s==d) ? 0.f : ew[e];
  atomicAdd(&deg[s], w);
  atomicAdd(&cnt[d], 1);
}

__global__ void k_dis(const float* __restrict__ deg, float* __restrict__ dis){
  int n = blockIdx.x*blockDim.x + threadIdx.x;
  if(n >= N_) return;
  float dg = deg[n];
  dis[n] = dg > 0.f ? rsqrtf(dg) : 0.f;
}

__global__ void k_scan(const int* __restrict__ cnt, int* __restrict__ offs){
  __shared__ int sums[256];
  int tid = threadIdx.x;
  int base = tid*8;
  int loc[8]; int s = 0;
  #pragma unroll
  for(int j=0;j<8;j++){ loc[j]=s; s += cnt[base+j]; }
  sums[tid] = s; __syncthreads();
  for(int ofs=1; ofs<256; ofs<<=1){
    int t = (tid>=ofs) ? sums[tid-ofs] : 0;
    __syncthreads();
    sums[tid] += t;
    __syncthreads();
  }
  int ebase = (tid==0) ? 0 : sums[tid-1];
  #pragma unroll
  for(int j=0;j<8;j++) offs[base+j] = ebase + loc[j];
  if(tid==255) offs[N_] = sums[255];
}

__global__ void k_fill(const int* __restrict__ src, const int* __restrict__ dst,
                       const float* __restrict__ ew, const float* __restrict__ dis,
                       const int* __restrict__ offs, int* fillc,
                       int2* __restrict__ epack){
  int e = blockIdx.x*blockDim.x + threadIdx.x;
  if(e >= E_) return;
  int s = src[e], d = dst[e];
  float w = (s==d) ? 0.f : ew[e];
  float wn = -dis[s]*w*dis[d];
  int pos = offs[d] + atomicAdd(&fillc[d], 1);
  epack[pos] = make_int2(s, __float_as_int(wn));
}

// ---- weight prepack into MFMA B-fragment layout (bf16) ----
// chunk c -> m=c>>1; baked: m=0 -> W0-W2, m=1 -> W1, m=2 -> 2*W2
__global__ void k_prep_cheb(const float* __restrict__ cw, ushort_* __restrict__ Bp){
  int i = blockIdx.x*blockDim.x + threadIdx.x;
  if(i >= 6*4*64) return;
  int lane = i & 63; int cn = i >> 6; int c = cn >> 2; int n = cn & 3;
  #pragma unroll
  for(int j=0;j<8;j++){
    int k = c*32 + (lane>>4)*8 + j;   // 0..191
    int h = k & 63; int m = k >> 6;
    int col = n*16 + (lane&15);
    float v;
    if(m == 0)      v = cw[(size_t)h*64 + col] - cw[(size_t)(128+h)*64 + col];
    else if(m == 1) v = cw[(size_t)(64+h)*64 + col];
    else            v = 2.f*cw[(size_t)(128+h)*64 + col];
    Bp[(size_t)i*8 + j] = f2b(v);
  }
}
__global__ void k_prep_conv2(const float* __restrict__ w2, ushort_* __restrict__ Bp2){
  int i = blockIdx.x*blockDim.x + threadIdx.x;
  if(i >= 6*8*64) return;
  int lane = i & 63; int cn = i >> 6; int c = cn >> 3; int n = cn & 7;
  #pragma unroll
  for(int j=0;j<8;j++){
    int k = c*32 + (lane>>4)*8 + j;
    int co = n*16 + (lane&15);
    int kt = k >> 6, ci = k & 63;
    Bp2[(size_t)i*8 + j] = f2b(w2[(size_t)co*192 + ci*3 + kt]);
  }
}

// ---------------- temporal conv 1 + GLU -> bf16, interleaved [n][g][c] ----------------
// one wave = (bt, 8 nodes); X addresses wave-uniform -> scalar loads
__global__ void k_conv1(const float* __restrict__ X, const float* __restrict__ w1,
                        const float* __restrict__ b1, ushort_* __restrict__ t0){
  int wv = rfl_(blockIdx.x*4 + (threadIdx.x>>6));
  int lane = threadIdx.x & 63;
  int nb = wv % (N_/8); int bt = wv / (N_/8); int b = bt / T1_; int t = bt % T1_;
  int n0 = nb*8;
  const float* Xp = X + ((size_t)((b*T_ + t)*N_ + n0))*CIN_;
  // per-lane weights for its output channel
  float wp[6], wq[6];
  #pragma unroll
  for(int k=0;k<6;k++){
    wp[k] = w1[ lane      *6 + k];   // k = ci*3 + kt
    wq[k] = w1[(lane+H_)*6 + k];
  }
  float bp = b1[lane], bq = b1[lane+H_];
  #pragma unroll
  for(int j=0;j<8;j++){
    float yp = bp, yq = bq;
    #pragma unroll
    for(int kt=0;kt<KT_;kt++)
      #pragma unroll
      for(int ci=0;ci<CIN_;ci++){
        float x = Xp[kt*(N_*CIN_) + j*CIN_ + ci];
        yp += x * wp[ci*3+kt];
        yq += x * wq[ci*3+kt];
      }
    float xin = (lane < CIN_) ? Xp[2*(N_*CIN_) + j*CIN_ + lane] : 0.f;
    t0[(size_t)(n0+j)*GS_ + (size_t)bt*H_ + lane] = f2b((yp + xin) * sigmoidf_(yq));
  }
}

// ---------------- SpMM interleaved: out = L zin. 8 graphs/wave, 16B gathers, XCD-swizzled ----
__global__ void k_spmm3(const ushort_* __restrict__ zin, ushort_* __restrict__ out,
                        const int* __restrict__ offs, const int2* __restrict__ epack){
  int lane = threadIdx.x & 63;
  int wv = threadIdx.x >> 6;
  int bid = blockIdx.x;                 // 14*512 = 7168
  int work = (bid & 7)*896 + (bid >> 3);
  int gg = work >> 9;                   // 0..13
  int dblk = work & 511;
  int d = dblk*4 + wv;
  int e0 = offs[d], e1 = offs[d+1];
  size_t lo = (size_t)(gg*8)*H_ + lane*8;
  const ushort_* zb = zin + lo;
  float ac[8] = {};
  #pragma unroll 2
  for(int i=e0;i<e1;i++){
    int2 e = epack[i];
    float w = __int_as_float(e.y);
    u16x8 zv = *(const u16x8*)(zb + (size_t)e.x*GS_);
    #pragma unroll
    for(int j=0;j<8;j++) ac[j] += w*b2f(zv[j]);
  }
  u16x8 ov;
  #pragma unroll
  for(int j=0;j<8;j++) ov[j] = f2b(ac[j]);
  *(u16x8*)(out + (size_t)d*GS_ + lo) = ov;
}

// ---------------- cheb fused GEMM via MFMA (interleaved A, LDS-staged B) ----------------
// tg = relu(bias + t0*(W0-W2) + tx1*W1 + y2*(2W2)); weights pre-baked in Bp.
__global__ __launch_bounds__(256) void k_cheb_mfma(
    const ushort_* __restrict__ t0, const ushort_* __restrict__ tx1,
    const ushort_* __restrict__ y2, const ushort_* __restrict__ Bp,
    const float* __restrict__ bias, ushort_* __restrict__ tg){
  __shared__ ushort_ lb[6*4*64*8];  // 24576 ushorts = 48 KB? no: 12288*2B = 24 KB
  int tid = threadIdx.x;
  #pragma unroll
  for(int i=0;i<6;i++)
    *(u16x8*)(lb + i*2048 + tid*8) = *(const u16x8*)(Bp + i*2048 + tid*8);
  __syncthreads();
  int lane = tid & 63;
  int wv = tid >> 6;
  int g = blockIdx.x >> 4;
  int row0 = (blockIdx.x & 15)*128 + wv*32;
  int ra = row0 + (lane&15);
  // hoist all 12 A fragments (one latency exposure)
  bf16x8 a[2][6];
  #pragma unroll
  for(int c=0;c<6;c++){
    const ushort_* s = (c>>1)==0 ? t0 : ((c>>1)==1 ? tx1 : y2);
    int eoff = (c&1)*32 + (lane>>4)*8;
    const ushort_* sb = s + (size_t)g*H_ + eoff;
    a[0][c] = *(const bf16x8*)(sb + (size_t)ra*GS_);
    a[1][c] = *(const bf16x8*)(sb + (size_t)(ra+16)*GS_);
  }
  f32x4 acc[2][4] = {};
  #pragma unroll
  for(int c=0;c<6;c++){
    #pragma unroll
    for(int n=0;n<4;n++){
      bf16x8 bfr = *(const bf16x8*)(lb + ((c*4+n)*64 + lane)*8);
      acc[0][n] = __builtin_amdgcn_mfma_f32_16x16x32_bf16(a[0][c], bfr, acc[0][n], 0,0,0);
      acc[1][n] = __builtin_amdgcn_mfma_f32_16x16x32_bf16(a[1][c], bfr, acc[1][n], 0,0,0);
    }
  }
  #pragma unroll
  for(int rg=0; rg<2; rg++)
    #pragma unroll
    for(int n=0;n<4;n++){
      int col = n*16 + (lane&15);
      float bv = bias[col];
      #pragma unroll
      for(int r=0;r<4;r++){
        int row = row0 + rg*16 + (lane>>4)*4 + r;
        float v = fmaxf(acc[rg][n][r] + bv, 0.f);
        tg[(size_t)(g*N_+row)*H_ + col] = f2b(v);
      }
    }
}

// ---------------- conv2 via MFMA (LDS-staged B, 32 rows/wave) ----------------
__global__ __launch_bounds__(256) void k_conv2_mfma(
    const ushort_* __restrict__ tg, const ushort_* __restrict__ Bp2,
    const float* __restrict__ b2, float* __restrict__ out){
  __shared__ ushort_ lb[6*8*64*8];  // 24576 ushorts = 48 KB
  int tid = threadIdx.x;
  #pragma unroll
  for(int i=0;i<12;i++)
    *(u16x8*)(lb + i*2048 + tid*8) = *(const u16x8*)(Bp2 + i*2048 + tid*8);
  __syncthreads();
  int lane = tid & 63;
  int wv = tid >> 6;
  int blk = blockIdx.x;          // 96*16
  int bt = blk >> 4; int nblk = blk & 15;
  int b = bt / T2_, t = bt % T2_;
  int n0 = nblk*128 + wv*32;
  const ushort_* base = tg + (size_t)(b*T1_ + t)*N_*H_;
  int ra = n0 + (lane&15);
  f32x4 acc[2][8] = {};
  #pragma unroll
  for(int c=0;c<6;c++){
    const ushort_* s = base + (size_t)(c>>1)*N_*H_;
    int eoff = (c&1)*32 + (lane>>4)*8;
    bf16x8 a0 = *(const bf16x8*)(s + (size_t)ra*H_ + eoff);
    bf16x8 a1 = *(const bf16x8*)(s + (size_t)(ra+16)*H_ + eoff);
    #pragma unroll
    for(int n=0;n<8;n++){
      bf16x8 bfr = *(const bf16x8*)(lb + ((c*8+n)*64 + lane)*8);
      acc[0][n] = __builtin_amdgcn_mfma_f32_16x16x32_bf16(a0, bfr, acc[0][n], 0,0,0);
      acc[1][n] = __builtin_amdgcn_mfma_f32_16x16x32_bf16(a1, bfr, acc[1][n], 0,0,0);
    }
  }
  const ushort_* xslab = base + (size_t)2*N_*H_;
  float* ob = out + (size_t)(b*T2_ + t)*N_*H_;
  #pragma unroll
  for(int rg=0;rg<2;rg++)
    #pragma unroll
    for(int n=0;n<4;n++){
      int col = n*16 + (lane&15);
      float bp = b2[col], bq = b2[col+COUT_];
      #pragma unroll
      for(int r=0;r<4;r++){
        int row = n0 + rg*16 + (lane>>4)*4 + r;
        float xin = b2f(xslab[(size_t)row*H_ + col]);
        float p = acc[rg][n][r] + bp + xin;
        float q = acc[rg][n+4][r] + bq;
        ob[(size_t)row*H_ + col] = p * sigmoidf_(q);
      }
    }
}

extern "C" void kernel_launch(void* const* d_in, const int* in_sizes, int n_in,
                              void* d_out, int out_size, void* d_ws, size_t ws_size,
                              hipStream_t stream){
  (void)in_sizes; (void)n_in; (void)out_size; (void)ws_size;
  const float* X  = (const float*)d_in[0];
  const int*   ei = (const int*)d_in[1];
  const float* ew = (const float*)d_in[2];
  const float* w1 = (const float*)d_in[3];
  const float* b1 = (const float*)d_in[4];
  const float* cw = (const float*)d_in[5];
  const float* cb = (const float*)d_in[6];
  const float* w2 = (const float*)d_in[7];
  const float* b2 = (const float*)d_in[8];
  float* out = (float*)d_out;

  char* ws = (char*)d_ws;
  const size_t BUF = (size_t)G_*N_*H_*sizeof(ushort_); // 29,360,128 B
  ushort_* t0  = (ushort_*)(ws);
  ushort_* tx1 = (ushort_*)(ws + BUF);
  ushort_* y2  = (ushort_*)(ws + 2*BUF);
  ushort_* tg  = (ushort_*)(ws + 3*BUF);
  char* sm = ws + 4*BUF;
  float* deg   = (float*)(sm);               // 8192
  float* dis   = (float*)(sm + 8192);        // 8192
  int*   cnt   = (int*)  (sm + 16384);       // 8192
  int*   fillc = (int*)  (sm + 24576);       // 8192
  int*   offs  = (int*)  (sm + 32768);       // 8448
  int2*  epack = (int2*) (sm + 41216);       // 262144
  ushort_* Bp  = (ushort_*)(sm + 41216 + 262144);          // 24576
  ushort_* Bp2 = (ushort_*)(sm + 41216 + 262144 + 24576);  // 49152

  const int* src = ei;
  const int* dst = ei + E_;

  k_zero   <<<N_/256, 256, 0, stream>>>(deg, cnt, fillc);
  k_deg_cnt<<<E_/256, 256, 0, stream>>>(src, dst, ew, deg, cnt);
  k_dis    <<<N_/256, 256, 0, stream>>>(deg, dis);
  k_scan   <<<1,      256, 0, stream>>>(cnt, offs);
  k_fill   <<<E_/256, 256, 0, stream>>>(src, dst, ew, dis, offs, fillc, epack);
  k_prep_cheb <<<6, 256, 0, stream>>>(cw, Bp);
  k_prep_conv2<<<12, 256, 0, stream>>>(w2, Bp2);

  // stage 1: temporal conv1 + GLU -> t0 (bf16, interleaved)
  k_conv1<<<(G_*N_/8)/4, 256, 0, stream>>>(X, w1, b1, t0);

  // tx1 = L t0 ; y2 = L tx1
  k_spmm3<<<14*512, 256, 0, stream>>>(t0,  tx1, offs, epack);
  k_spmm3<<<14*512, 256, 0, stream>>>(tx1, y2,  offs, epack);

  // tg = relu(bias + t0*(W0-W2) + tx1*W1 + y2*(2W2))   (MFMA, LDS B)
  k_cheb_mfma<<<G_*16, 256, 0, stream>>>(t0, tx1, y2, Bp, cb, tg);

  // stage 3: temporal conv2 + GLU -> out   (MFMA, LDS B)
  k_conv2_mfma<<<(B_*T2_)*16, 256, 0, stream>>>(tg, Bp2, b2, out);
}